// Round 10
// baseline (368.712 us; speedup 1.0000x reference)
//
#include <hip/hip_runtime.h>
#include <math.h>

#define NTOT  65536
#define NEDGE 524288
#define BGR   128
#define NPG   512
#define NL    32
#define F1    128
#define F2    96
#define F3    64
#define KT    16
#define BINS  16
#define BN    32
#define GCAP  6144   // per-graph edge bucket capacity (mean 4096, +32 sigma)

typedef unsigned short bf;
typedef __attribute__((ext_vector_type(8))) short sv8;    // 8 bf16 fragment (4 VGPRs)
typedef __attribute__((ext_vector_type(16))) float fv16;  // 32x32 mfma accumulator

// ---------------- helpers ----------------
__device__ __forceinline__ float b2f(bf v) { return __uint_as_float(((unsigned)v) << 16); }
__device__ __forceinline__ bf f2b(float f) {
    unsigned u = __float_as_uint(f);
    return (bf)((u + 0x7FFF + ((u >> 16) & 1)) >> 16);  // RNE
}
__device__ __forceinline__ float sigm(float x) { return 1.f / (1.f + expf(-x)); }

// ---------------- init: zero gcount + transpose/convert all weights ----------------
__global__ __launch_bounds__(256) void init_k(const float* __restrict__ W1, const float* __restrict__ W2,
                                              const float* __restrict__ W3,
                                              bf* __restrict__ T1, bf* __restrict__ T2, bf* __restrict__ T3,
                                              int* __restrict__ gcount) {
    int i = blockIdx.x * 256 + threadIdx.x;
    if (i < 256) gcount[i] = 0;
    if (i < NL * F1) {
        int co = i >> 5, ci = i & 31;
        T1[i] = f2b(W1[ci * F1 + co]);
    } else if (i < NL * F1 + F1 * F2) {
        int i2 = i - NL * F1;
        int co = i2 >> 7, ci = i2 & 127;
        T2[i2] = f2b(W2[ci * F2 + co]);
    } else if (i < NL * F1 + F1 * F2 + F2 * F3) {
        int i3 = i - NL * F1 - F1 * F2;
        int co = i3 / 96, ci = i3 - co * 96;
        T3[i3] = f2b(W3[ci * F3 + co]);
    }
}

// ---------------- CSR build: graph-bucket then per-graph sort ----------------
__global__ __launch_bounds__(256) void bucket_k(const int* __restrict__ ei1, const int* __restrict__ ei2,
                                                int* __restrict__ gcount, unsigned* __restrict__ bucket) {
    int side = blockIdx.y;
    const int* src = side ? ei2 : ei1;
    const int* dst = src + NEDGE;
    __shared__ int bc[128], bbase[128], bcur[128];
    int t = threadIdx.x;
    if (t < 128) { bc[t] = 0; bcur[t] = 0; }
    __syncthreads();
    int e0 = blockIdx.x * 1024;
    unsigned lp[4];
    int lg[4];
#pragma unroll
    for (int i = 0; i < 4; i++) {
        int e = e0 + i * 256 + t;
        int s = src[e], d = dst[e];
        int g = d >> 9;
        lp[i] = ((unsigned)s << 9) | (unsigned)(d & 511);
        lg[i] = g;
        atomicAdd(&bc[g], 1);
    }
    __syncthreads();
    if (t < 128 && bc[t] > 0) bbase[t] = atomicAdd(&gcount[side * 128 + t], bc[t]);
    __syncthreads();
#pragma unroll
    for (int i = 0; i < 4; i++) {
        int g = lg[i];
        int pos = bbase[g] + atomicAdd(&bcur[g], 1);
        if (pos < GCAP) bucket[((size_t)side * 128 + g) * GCAP + pos] = lp[i];
    }
}

__global__ void gscan_k(const int* __restrict__ gcount, int* __restrict__ gbase) {
    __shared__ int s[256];
    int t = threadIdx.x;
    int x = gcount[t];
    s[t] = x;
    __syncthreads();
    for (int o = 1; o < 128; o <<= 1) {
        int v = ((t & 127) >= o) ? s[t - o] : 0;
        __syncthreads();
        s[t] += v;
        __syncthreads();
    }
    gbase[t] = (t >> 7) * NEDGE + s[t] - x;
}

// Phase B: one block per graph; CSR built in LDS; edge record 4B: src(u16)|norm(bf16)<<16.
__global__ __launch_bounds__(256) void csr_k(const unsigned* __restrict__ bucket, const int* __restrict__ gcount,
                                             const int* __restrict__ gbase, int* __restrict__ off,
                                             float* __restrict__ dinv, unsigned* __restrict__ ecsr) {
    int side = blockIdx.y, g = blockIdx.x, t = threadIdx.x;
    __shared__ int ncnt[512];
    __shared__ int c2[256];
    __shared__ int cur[512];
    __shared__ float dloc[512];
    ncnt[t] = 0; ncnt[t + 256] = 0;
    __syncthreads();
    int cnt = gcount[side * 128 + g];
    cnt = cnt < GCAP ? cnt : GCAP;
    int base = gbase[side * 128 + g];
    const unsigned* bk = bucket + ((size_t)side * 128 + g) * GCAP;
    for (int i = t; i < cnt; i += 256) atomicAdd(&ncnt[bk[i] & 511], 1);
    __syncthreads();
    int e0 = ncnt[2 * t], e1 = ncnt[2 * t + 1];
    c2[t] = e0 + e1;
    __syncthreads();
    for (int o = 1; o < 256; o <<= 1) {
        int v = (t >= o) ? c2[t - o] : 0;
        __syncthreads();
        c2[t] += v;
        __syncthreads();
    }
    int ex = c2[t] - (e0 + e1);
    cur[2 * t] = ex;
    cur[2 * t + 1] = ex + e0;
    float d0 = rsqrtf((float)e0 + 1.f), d1 = rsqrtf((float)e1 + 1.f);
    dloc[2 * t] = d0; dloc[2 * t + 1] = d1;
    int node0 = g * NPG + 2 * t;
    int* offs = off + side * (NTOT + 1);
    offs[node0] = base + ex;
    offs[node0 + 1] = base + ex + e0;
    *(float2*)(dinv + (size_t)side * NTOT + node0) = make_float2(d0, d1);
    if (g == BGR - 1 && t == 0) offs[NTOT] = (side + 1) * NEDGE;
    __syncthreads();
    for (int i = t; i < cnt; i += 256) {
        unsigned p = bk[i];
        int dl = p & 511;
        int s = p >> 9;
        int pos = atomicAdd(&cur[dl], 1);
        float nm = dloc[s & 511] * dloc[dl];
        ecsr[base + pos] = (unsigned)s | ((unsigned)f2b(nm) << 16);
    }
}

// ---------------- fused layer 1 (LDS-staged): h1 = relu((A_hat x) W1 + b1) ----------------
// one block per (graph, side); x rows staged in LDS as bf16; gathers hit LDS.
__global__ __launch_bounds__(256) void aggemm1_k(const float* __restrict__ x1, const float* __restrict__ x2,
                                                 const int* __restrict__ off, const unsigned* __restrict__ ecsr,
                                                 const float* __restrict__ dinv,
                                                 const bf* __restrict__ wt1, const float* __restrict__ bias,
                                                 bf* __restrict__ outb) {
    __shared__ bf Xs[NPG * NL];  // 32 KB
    int g = blockIdx.x, side = blockIdx.y;
    const float* x = (side ? x2 : x1) + (size_t)g * NPG * NL;
    int t = threadIdx.x;
    for (int i = t; i < NPG * NL / 4; i += 256) {
        float4 v = *(const float4*)(x + (size_t)i * 4);
        ushort4 o;
        o.x = f2b(v.x); o.y = f2b(v.y); o.z = f2b(v.z); o.w = f2b(v.w);
        *(ushort4*)&Xs[i * 4] = o;
    }
    __syncthreads();
    const int* offs = off + side * (NTOT + 1) + g * NPG;
    const float* dv = dinv + (size_t)side * NTOT + g * NPG;
    bf* out = outb + ((size_t)side * NTOT + (size_t)g * NPG) * F1;
    int wave = t >> 6, lane = t & 63, half = lane >> 5, r = lane & 31;
    // hoist W1 fragments (4 col tiles x 2 K-blocks)
    sv8 wb0[4], wb1[4];
#pragma unroll
    for (int nt = 0; nt < 4; nt++) {
        const bf* Bp = wt1 + (size_t)(nt * 32 + r) * NL + half * 8;
        wb0[nt] = *(const sv8*)(Bp);
        wb1[nt] = *(const sv8*)(Bp + 16);
    }
    for (int st = 0; st < 4; st++) {
        int row0 = st * 128 + wave * 32;
        int n = row0 + r;
        float d = dv[n];
        float sc = d * d;
        float z[16];
        {
            ushort4 s0 = *(const ushort4*)&Xs[n * NL + half * 8];
            ushort4 s1 = *(const ushort4*)&Xs[n * NL + half * 8 + 4];
            ushort4 s2 = *(const ushort4*)&Xs[n * NL + 16 + half * 8];
            ushort4 s3 = *(const ushort4*)&Xs[n * NL + 16 + half * 8 + 4];
            z[0] = b2f(s0.x) * sc; z[1] = b2f(s0.y) * sc; z[2] = b2f(s0.z) * sc; z[3] = b2f(s0.w) * sc;
            z[4] = b2f(s1.x) * sc; z[5] = b2f(s1.y) * sc; z[6] = b2f(s1.z) * sc; z[7] = b2f(s1.w) * sc;
            z[8] = b2f(s2.x) * sc; z[9] = b2f(s2.y) * sc; z[10] = b2f(s2.z) * sc; z[11] = b2f(s2.w) * sc;
            z[12] = b2f(s3.x) * sc; z[13] = b2f(s3.y) * sc; z[14] = b2f(s3.z) * sc; z[15] = b2f(s3.w) * sc;
        }
        int e0 = offs[n], e1 = offs[n + 1];
        for (int j = e0; j < e1; j++) {
            unsigned en = ecsr[j];
            int lcl = en & 511;
            float w = b2f((bf)(en >> 16));
            ushort4 u0 = *(const ushort4*)&Xs[lcl * NL + half * 8];
            ushort4 u1 = *(const ushort4*)&Xs[lcl * NL + half * 8 + 4];
            ushort4 u2 = *(const ushort4*)&Xs[lcl * NL + 16 + half * 8];
            ushort4 u3 = *(const ushort4*)&Xs[lcl * NL + 16 + half * 8 + 4];
            z[0] += w * b2f(u0.x); z[1] += w * b2f(u0.y); z[2] += w * b2f(u0.z); z[3] += w * b2f(u0.w);
            z[4] += w * b2f(u1.x); z[5] += w * b2f(u1.y); z[6] += w * b2f(u1.z); z[7] += w * b2f(u1.w);
            z[8] += w * b2f(u2.x); z[9] += w * b2f(u2.y); z[10] += w * b2f(u2.z); z[11] += w * b2f(u2.w);
            z[12] += w * b2f(u3.x); z[13] += w * b2f(u3.y); z[14] += w * b2f(u3.z); z[15] += w * b2f(u3.w);
        }
        sv8 a0, a1;
#pragma unroll
        for (int jj = 0; jj < 8; jj++) {
            a0[jj] = (short)f2b(z[jj]);
            a1[jj] = (short)f2b(z[8 + jj]);
        }
#pragma unroll
        for (int nt = 0; nt < 4; nt++) {
            fv16 acc;
#pragma unroll
            for (int i = 0; i < 16; i++) acc[i] = 0.f;
            acc = __builtin_amdgcn_mfma_f32_32x32x16_bf16(a0, wb0[nt], acc, 0, 0, 0);
            acc = __builtin_amdgcn_mfma_f32_32x32x16_bf16(a1, wb1[nt], acc, 0, 0, 0);
            float bv = bias[nt * 32 + r];
#pragma unroll
            for (int i = 0; i < 16; i++) {
                int rr = (i & 3) + 8 * (i >> 2) + 4 * half;
                float v = fmaxf(acc[i] + bv, 0.f);
                out[(size_t)(row0 + rr) * F1 + nt * 32 + r] = f2b(v);
            }
        }
    }
}

// ---------------- MFMA GEMM (both sides via blockIdx.y) ----------------
template <int CIN, int COUT, int BIAS, int RELU>
__global__ __launch_bounds__(256) void gemmm_k(const bf* __restrict__ Xb, const bf* __restrict__ Wt,
                                               const float* __restrict__ bias, bf* __restrict__ outb) {
    int side = blockIdx.y;
    const bf* X = Xb + (size_t)side * NTOT * CIN;
    bf* out = outb + (size_t)side * NTOT * COUT;
    int wave = threadIdx.x >> 6, lane = threadIdx.x & 63;
    int half = lane >> 5, r = lane & 31;
    int row0 = blockIdx.x * 128 + wave * 32;
    const bf* Ap = X + (size_t)(row0 + r) * CIN + half * 8;
    sv8 a[CIN / 16];
#pragma unroll
    for (int k = 0; k < CIN / 16; k++) a[k] = *(const sv8*)(Ap + k * 16);
#pragma unroll
    for (int nt = 0; nt < COUT / 32; nt++) {
        const bf* Bp = Wt + (size_t)(nt * 32 + r) * CIN + half * 8;
        fv16 acc;
#pragma unroll
        for (int i = 0; i < 16; i++) acc[i] = 0.f;
#pragma unroll
        for (int k = 0; k < CIN / 16; k++)
            acc = __builtin_amdgcn_mfma_f32_32x32x16_bf16(a[k], *(const sv8*)(Bp + k * 16), acc, 0, 0, 0);
        float bv = BIAS ? bias[nt * 32 + r] : 0.f;
#pragma unroll
        for (int i = 0; i < 16; i++) {
            int rr = (i & 3) + 8 * (i >> 2) + 4 * half;
            float v = acc[i] + bv;
            if (RELU) v = fmaxf(v, 0.f);
            out[(size_t)(row0 + rr) * COUT + nt * 32 + r] = f2b(v);
        }
    }
}

// ---------------- LDS-staged GCN aggregation ----------------
// grid (BGR, 2 sides, 2 feature-halves). Block stages 512 x CH cols in LDS;
// gathers hit LDS. OUTSEL=1 -> write f1/f2, else outb.
template <int C, int RELU, int OUTSEL>
__global__ __launch_bounds__(256) void agg_k(const bf* __restrict__ hinb, const float* __restrict__ bias,
                                             const int* __restrict__ off, const unsigned* __restrict__ ecsr,
                                             const float* __restrict__ dinv, bf* __restrict__ outb,
                                             bf* __restrict__ f1, bf* __restrict__ f2) {
    constexpr int CH = C / 2;
    constexpr int CHUNKS = CH / 8;   // 16B chunks per row
    constexpr int Q = CH / 4;
    __shared__ bf Hs[NPG * CH];      // 48 KB (C=96) / 32 KB (C=64)
    int g = blockIdx.x, side = blockIdx.y, ch = blockIdx.z;
    const bf* hin = hinb + ((size_t)side * NTOT + (size_t)g * NPG) * C + ch * CH;
    int t = threadIdx.x;
    for (int i = t; i < NPG * CHUNKS; i += 256) {
        int row = i / CHUNKS, cc = i - row * CHUNKS;
        *(uint4*)&Hs[row * CH + cc * 8] = *(const uint4*)(hin + (size_t)row * C + cc * 8);
    }
    __syncthreads();
    const int* offs = off + side * (NTOT + 1) + g * NPG;
    const float* dv = dinv + (size_t)side * NTOT + g * NPG;
    bf* out;
    if (OUTSEL) out = side ? f2 : f1;
    else out = outb + (size_t)side * NTOT * C;
    out += (size_t)g * NPG * C + ch * CH;
    const float* bs = bias + ch * CH;
    for (int item = t; item < NPG * Q; item += 256) {
        int node = item / Q, q = (item - node * Q) * 4;
        float d = dv[node];
        float sc = d * d;
        ushort4 h = *(const ushort4*)&Hs[node * CH + q];
        float ax = b2f(h.x) * sc, ay = b2f(h.y) * sc, az = b2f(h.z) * sc, aw = b2f(h.w) * sc;
        int e0 = offs[node], e1 = offs[node + 1];
        int j = e0;
        for (; j + 2 <= e1; j += 2) {
            unsigned ena = ecsr[j], enb = ecsr[j + 1];
            int la = ena & 511, lb = enb & 511;
            float wa = b2f((bf)(ena >> 16)), wb = b2f((bf)(enb >> 16));
            ushort4 ha = *(const ushort4*)&Hs[la * CH + q];
            ushort4 hb = *(const ushort4*)&Hs[lb * CH + q];
            ax += wa * b2f(ha.x) + wb * b2f(hb.x);
            ay += wa * b2f(ha.y) + wb * b2f(hb.y);
            az += wa * b2f(ha.z) + wb * b2f(hb.z);
            aw += wa * b2f(ha.w) + wb * b2f(hb.w);
        }
        if (j < e1) {
            unsigned en = ecsr[j];
            int lc = en & 511;
            float w = b2f((bf)(en >> 16));
            ushort4 hs = *(const ushort4*)&Hs[lc * CH + q];
            ax += w * b2f(hs.x); ay += w * b2f(hs.y); az += w * b2f(hs.z); aw += w * b2f(hs.w);
        }
        float4 bv = *(const float4*)(bs + q);
        ax += bv.x; ay += bv.y; az += bv.z; aw += bv.w;
        if (RELU) {
            ax = fmaxf(ax, 0.f); ay = fmaxf(ay, 0.f); az = fmaxf(az, 0.f); aw = fmaxf(aw, 0.f);
        }
        ushort4 o;
        o.x = f2b(ax); o.y = f2b(ay); o.z = f2b(az); o.w = f2b(aw);
        *(ushort4*)(out + (size_t)node * C + q) = o;
    }
}

// ---------------- sim tile core ----------------
__device__ __forceinline__ void sim_tile(const bf* __restrict__ f1, const bf* __restrict__ f2,
                                         int g, int mt, int wave, int lane, fv16 acc[4],
                                         sv8& a0, sv8& a1, sv8& a2, sv8& a3) {
    int half = lane >> 5, r = lane & 31;
    const bf* Ap = f1 + ((size_t)g * NPG + mt * 32 + r) * F3 + half * 8;
    a0 = *(const sv8*)(Ap +  0);
    a1 = *(const sv8*)(Ap + 16);
    a2 = *(const sv8*)(Ap + 32);
    a3 = *(const sv8*)(Ap + 48);
#pragma unroll
    for (int j = 0; j < 4; j++) {
        int nt = j * 4 + wave;
        const bf* Bp = f2 + ((size_t)g * NPG + nt * 32 + r) * F3 + half * 8;
#pragma unroll
        for (int i = 0; i < 16; i++) acc[j][i] = 0.f;
        acc[j] = __builtin_amdgcn_mfma_f32_32x32x16_bf16(a0, *(const sv8*)(Bp +  0), acc[j], 0, 0, 0);
        acc[j] = __builtin_amdgcn_mfma_f32_32x32x16_bf16(a1, *(const sv8*)(Bp + 16), acc[j], 0, 0, 0);
        acc[j] = __builtin_amdgcn_mfma_f32_32x32x16_bf16(a2, *(const sv8*)(Bp + 32), acc[j], 0, 0, 0);
        acc[j] = __builtin_amdgcn_mfma_f32_32x32x16_bf16(a3, *(const sv8*)(Bp + 48), acc[j], 0, 0, 0);
    }
}

// ---------------- combo: simm (blocks 0..2047) + meanp (blocks 2048..4095) ----------------
__global__ __launch_bounds__(256) void simmean_k(const bf* __restrict__ f1, const bf* __restrict__ f2,
                                                 float* __restrict__ statmin, float* __restrict__ statmax,
                                                 float* __restrict__ meanp) {
    __shared__ float red[256];
    int bid = blockIdx.x;
    int t = threadIdx.x, wave = t >> 6, lane = t & 63;
    if (bid < 2048) {
        int g = bid >> 4, mt = bid & 15;
        fv16 acc[4];
        sv8 a0, a1, a2, a3;
        sim_tile(f1, f2, g, mt, wave, lane, acc, a0, a1, a2, a3);
        float mn = 1e30f, mx = -1e30f;
#pragma unroll
        for (int j = 0; j < 4; j++)
#pragma unroll
            for (int i = 0; i < 16; i++) {
                mn = fminf(mn, acc[j][i]);
                mx = fmaxf(mx, acc[j][i]);
            }
        for (int o = 32; o; o >>= 1) {
            mn = fminf(mn, __shfl_down(mn, o));
            mx = fmaxf(mx, __shfl_down(mx, o));
        }
        if (lane == 0) { red[wave] = mn; red[4 + wave] = mx; }
        __syncthreads();
        if (t == 0) {
            statmin[g * 16 + mt] = fminf(fminf(red[0], red[1]), fminf(red[2], red[3]));
            statmax[g * 16 + mt] = fmaxf(fmaxf(red[4], red[5]), fmaxf(red[6], red[7]));
        }
    } else {
        int idx = bid - 2048;
        int side = idx >> 10, rem = idx & 1023;
        int ch = rem >> 7, g = rem & 127;
        const bf* xp = (side ? f2 : f1) + ((size_t)g * NPG + ch * 64) * F3;
        int f = t & 63;
        float m = 0.f;
#pragma unroll 4
        for (int i = 0; i < 16; i++) m += b2f(xp[(size_t)(wave * 16 + i) * F3 + f]);
        red[t] = m;
        __syncthreads();
        if (t < 64) meanp[(((size_t)side * BGR + g) * 8 + ch) * 64 + t] =
            red[t] + red[64 + t] + red[128 + t] + red[192 + t];
    }
}

// ---------------- combo: simh (blocks 0..2047) + ctx (blocks 2048..2303) ----------------
__global__ __launch_bounds__(256) void simhctx_k(const bf* __restrict__ f1, const bf* __restrict__ f2,
                                                 const float* __restrict__ statmin, const float* __restrict__ statmax,
                                                 int* __restrict__ hist_p,
                                                 const float* __restrict__ meanp, const float* __restrict__ Watt,
                                                 float* __restrict__ ctxb) {
    __shared__ int ph[256 * 17];
    __shared__ int pr[256];
    int bid = blockIdx.x;
    int t = threadIdx.x, wave = t >> 6, lane = t & 63;
    if (bid < 2048) {
        int g = bid >> 4, mt = bid & 15;
#pragma unroll
        for (int b = 0; b < BINS; b++) ph[t * 17 + b] = 0;
        float pm = (lane < 16) ? statmin[g * 16 + lane] : 1e30f;
        float px = (lane < 16) ? statmax[g * 16 + lane] : -1e30f;
        for (int o = 8; o; o >>= 1) {
            pm = fminf(pm, __shfl_down(pm, o));
            px = fmaxf(px, __shfl_down(px, o));
        }
        float vmin = sigm(__shfl(pm, 0));
        float vmax = sigm(__shfl(px, 0));
        float width = (vmax - vmin) / (float)BINS;
        float inv = 1.0f / (width > 0.f ? width : 1.0f);
        fv16 acc[4];
        sv8 a0, a1, a2, a3;
        sim_tile(f1, f2, g, mt, wave, lane, acc, a0, a1, a2, a3);
#pragma unroll
        for (int j = 0; j < 4; j++)
#pragma unroll
            for (int i = 0; i < 16; i++) {
                float v = sigm(acc[j][i]);
                int bi = (int)floorf((v - vmin) * inv);
                bi = bi < 0 ? 0 : (bi > BINS - 1 ? BINS - 1 : bi);
                ph[t * 17 + bi] += 1;
            }
        __syncthreads();
        {
            int grp = t >> 4, bin = t & 15;
            int s = 0;
#pragma unroll
            for (int j = 0; j < 16; j++) s += ph[(grp * 16 + j) * 17 + bin];
            pr[t] = s;
        }
        __syncthreads();
        if (t < BINS) {
            int tot = 0;
#pragma unroll
            for (int j = 0; j < 16; j++) tot += pr[j * 16 + t];
            hist_p[((size_t)g * 16 + mt) * BINS + t] = tot;
        }
    } else {
        int idx = bid - 2048;
        int side = idx >> 7, g = idx & 127;
        float* sm = (float*)pr;
        if (t < 64) {
            float m = 0.f;
#pragma unroll
            for (int ch = 0; ch < 8; ch++) m += meanp[(((size_t)side * BGR + g) * 8 + ch) * 64 + t];
            sm[t] = m * (1.0f / (float)NPG);
        }
        __syncthreads();
        if (t < 64) {
            float acc = 0.f;
#pragma unroll 8
            for (int i = 0; i < F3; i++) acc += sm[i] * Watt[i * F3 + t];
            ctxb[((size_t)side * BGR + g) * F3 + t] = tanhf(acc);
        }
    }
}

// coef + weighted partial pool; grid (BGR, 8, 2)
__global__ __launch_bounds__(256) void cpool_k(const bf* __restrict__ f1, const bf* __restrict__ f2,
                                               const float* __restrict__ ctxb, float* __restrict__ poolp) {
    int g = blockIdx.x, ch = blockIdx.y, side = blockIdx.z;
    const bf* xp = (side ? f2 : f1) + ((size_t)g * NPG + ch * 64) * F3;
    int t = threadIdx.x, w = t >> 6, f = t & 63;
    float cx = ctxb[((size_t)side * BGR + g) * F3 + f];
    float acc = 0.f;
    for (int i = 0; i < 16; i++) {
        float v = b2f(xp[(size_t)(w * 16 + i) * F3 + f]);
        float d = v * cx;
#pragma unroll
        for (int o = 1; o < 64; o <<= 1) d += __shfl_xor(d, o);
        acc += sigm(d) * v;
    }
    __shared__ float red[256];
    red[t] = acc;
    __syncthreads();
    if (t < 64) poolp[(((size_t)side * BGR + g) * 8 + ch) * 64 + t] =
        red[t] + red[64 + t] + red[128 + t] + red[192 + t];
}

// ---------------- tensor network + tail MLP ----------------
__global__ __launch_bounds__(256) void final_k(const float* __restrict__ poolp,
                                               const float* __restrict__ Wt, const float* __restrict__ Wtb,
                                               const float* __restrict__ tb, const int* __restrict__ hist_p,
                                               const float* __restrict__ W1, const float* __restrict__ b1,
                                               const float* __restrict__ Ws, const float* __restrict__ bs,
                                               float* __restrict__ out) {
    int b = blockIdx.x, t = threadIdx.x;
    __shared__ float cat[128];
    __shared__ float sacc[256];
    __shared__ float feat[32];
    __shared__ float hb[32];
    if (t < 128) {
        int side = t >> 6, f = t & 63;
        float s = 0.f;
#pragma unroll
        for (int ch = 0; ch < 8; ch++) s += poolp[(((size_t)side * BGR + b) * 8 + ch) * 64 + f];
        cat[t] = s;
    }
    __syncthreads();
    int k = t & 15, c = t >> 4;
    float acc = 0.f;
    for (int q = 0; q < 256; q++) {
        int ij = c * 256 + q;
        int i = ij >> 6, j = ij & 63;
        acc += cat[i] * cat[64 + j] * Wt[ij * KT + k];
    }
    sacc[t] = acc;
    __syncthreads();
    if (t < KT) {
        float sc = 0.f;
        for (int c2 = 0; c2 < 16; c2++) sc += sacc[c2 * 16 + t];
        float bt = 0.f;
        for (int i = 0; i < 128; i++) bt += cat[i] * Wtb[t * 128 + i];
        float tv = sc + bt + tb[t];
        feat[t] = tv > 0.f ? tv : 0.f;
        int hsum = 0;
#pragma unroll
        for (int j = 0; j < 16; j++) hsum += hist_p[((size_t)b * 16 + j) * BINS + t];
        feat[KT + t] = (float)hsum * (1.0f / (float)(NPG * NPG));
    }
    __syncthreads();
    if (t < BN) {
        float a = 0.f;
        for (int i = 0; i < KT + BINS; i++) a += feat[i] * W1[i * BN + t];
        a += b1[t];
        hb[t] = a > 0.f ? a : 0.f;
    }
    __syncthreads();
    if (t == 0) {
        float s = bs[0];
        for (int j = 0; j < BN; j++) s += hb[j] * Ws[j];
        out[b] = sigm(s);
    }
}

// ---------------- launch ----------------
extern "C" void kernel_launch(void* const* d_in, const int* in_sizes, int n_in,
                              void* d_out, int out_size, void* d_ws, size_t ws_size,
                              hipStream_t stream) {
    const float* x1   = (const float*)d_in[0];
    const float* x2   = (const float*)d_in[1];
    const int*   ei1  = (const int*)d_in[2];
    const int*   ei2  = (const int*)d_in[3];
    const float* Wc1  = (const float*)d_in[6];
    const float* bc1  = (const float*)d_in[7];
    const float* Wc2  = (const float*)d_in[8];
    const float* bc2  = (const float*)d_in[9];
    const float* Wc3  = (const float*)d_in[10];
    const float* bc3  = (const float*)d_in[11];
    const float* Watt = (const float*)d_in[12];
    const float* Wt   = (const float*)d_in[13];
    const float* Wtb  = (const float*)d_in[14];
    const float* tb   = (const float*)d_in[15];
    const float* W1   = (const float*)d_in[16];
    const float* b1   = (const float*)d_in[17];
    const float* Ws   = (const float*)d_in[18];
    const float* bs   = (const float*)d_in[19];
    float* out = (float*)d_out;

    // ---- workspace layout (~100 MB) ----
    char* wsb = (char*)d_ws;
    size_t o = 0;
    auto alloc = [&](size_t bytes) -> void* {
        void* p = wsb + o;
        o = (o + bytes + 255) & ~(size_t)255;
        return p;
    };
    bf* f1b  = (bf*)alloc((size_t)NTOT * F3 * 2);     //  8 MB
    bf* f2b  = (bf*)alloc((size_t)NTOT * F3 * 2);     //  8 MB
    bf* X    = (bf*)alloc((size_t)2 * NTOT * F1 * 2); // 32 MB (both sides)
    bf* Y    = (bf*)alloc((size_t)2 * NTOT * F2 * 2); // 24 MB (both sides)
    int* off   = (int*)alloc((size_t)2 * (NTOT + 1) * 4);
    unsigned* ecsr = (unsigned*)alloc((size_t)2 * NEDGE * 4);        // 4 MB packed src|norm
    unsigned* bucket = (unsigned*)alloc((size_t)2 * 128 * GCAP * 4); // 6.3 MB
    int* gcount = (int*)alloc(256 * 4);
    int* gbase  = (int*)alloc(256 * 4);
    float* dinv = (float*)alloc((size_t)2 * NTOT * 4);
    float* statmin = (float*)alloc((size_t)BGR * 16 * 4);
    float* statmax = (float*)alloc((size_t)BGR * 16 * 4);
    int* hist_p = (int*)alloc((size_t)BGR * 16 * BINS * 4);
    float* meanp = (float*)alloc((size_t)2 * BGR * 8 * 64 * 4);
    float* ctx   = (float*)alloc((size_t)2 * BGR * F3 * 4);
    float* poolp = (float*)alloc((size_t)2 * BGR * 8 * 64 * 4);
    bf* wt1 = (bf*)alloc((size_t)NL * F1 * 2);   // Wt1[F1][NL]
    bf* wt2 = (bf*)alloc((size_t)F1 * F2 * 2);   // Wt2[F2][F1]
    bf* wt3 = (bf*)alloc((size_t)F2 * F3 * 2);   // Wt3[F3][F2]
    (void)ws_size; (void)in_sizes; (void)n_in; (void)out_size;

    // init: zero gcount + weight transpose (single dispatch)
    init_k<<<(NL * F1 + F1 * F2 + F2 * F3 + 255) / 256, 256, 0, stream>>>(Wc1, Wc2, Wc3, wt1, wt2, wt3, gcount);

    // ---- CSR build: bucket by graph, scan, per-graph sort ----
    bucket_k<<<dim3(NEDGE / 1024, 2), 256, 0, stream>>>(ei1, ei2, gcount, bucket);
    gscan_k<<<1, 256, 0, stream>>>(gcount, gbase);
    csr_k<<<dim3(BGR, 2), 256, 0, stream>>>(bucket, gcount, gbase, off, dinv, ecsr);

    // ---- GCN stack: both sides batched per layer; gathers staged in LDS ----
    // h1 = relu((A_hat x) W1 + b1) -> X
    aggemm1_k<<<dim3(BGR, 2), 256, 0, stream>>>(x1, x2, off, ecsr, dinv, wt1, bc1, X);
    // t2 = h1 Wc2 -> Y
    gemmm_k<F1, F2, 0, 0><<<dim3(NTOT / 128, 2), 256, 0, stream>>>(X, wt2, nullptr, Y);
    // h2 = relu(A_hat t2 + bc2) -> X
    agg_k<F2, 1, 0><<<dim3(BGR, 2, 2), 256, 0, stream>>>(Y, bc2, off, ecsr, dinv, X, nullptr, nullptr);
    // t3 = h2 Wc3 -> Y
    gemmm_k<F2, F3, 0, 0><<<dim3(NTOT / 128, 2), 256, 0, stream>>>(X, wt3, nullptr, Y);
    // f = A_hat t3 + bc3 -> f1b/f2b
    agg_k<F3, 0, 1><<<dim3(BGR, 2, 2), 256, 0, stream>>>(Y, bc3, off, ecsr, dinv, nullptr, f1b, f2b);

    // ---- sim minmax + mean partials (one dispatch) ----
    simmean_k<<<4096, 256, 0, stream>>>(f1b, f2b, statmin, statmax, meanp);
    // ---- sim hist + ctx (one dispatch) ----
    simhctx_k<<<2048 + 256, 256, 0, stream>>>(f1b, f2b, statmin, statmax, hist_p, meanp, Watt, ctx);
    // ---- coef + weighted pool partials ----
    cpool_k<<<dim3(BGR, 8, 2), 256, 0, stream>>>(f1b, f2b, ctx, poolp);

    // ---- tensor network + MLP tail ----
    final_k<<<BGR, 256, 0, stream>>>(poolp, Wt, Wtb, tb, hist_p, W1, b1, Ws, bs, out);
}

// Round 11
// 350.616 us; speedup vs baseline: 1.0516x; 1.0516x over previous
//
#include <hip/hip_runtime.h>
#include <math.h>

#define NTOT  65536
#define NEDGE 524288
#define BGR   128
#define NPG   512
#define NL    32
#define F1    128
#define F2    96
#define F3    64
#define KT    16
#define BINS  16
#define BN    32
#define GCAP  6144   // per-graph edge bucket capacity (mean 4096, +32 sigma)

typedef unsigned short bf;
typedef __attribute__((ext_vector_type(8))) short sv8;    // 8 bf16 fragment (4 VGPRs)
typedef __attribute__((ext_vector_type(16))) float fv16;  // 32x32 mfma accumulator

// ---------------- helpers ----------------
__device__ __forceinline__ float b2f(bf v) { return __uint_as_float(((unsigned)v) << 16); }
__device__ __forceinline__ bf f2b(float f) {
    unsigned u = __float_as_uint(f);
    return (bf)((u + 0x7FFF + ((u >> 16) & 1)) >> 16);  // RNE
}
__device__ __forceinline__ float sigm(float x) { return 1.f / (1.f + expf(-x)); }

// ---------------- init: zero gcount + transpose/convert all weights ----------------
__global__ __launch_bounds__(256) void init_k(const float* __restrict__ W1, const float* __restrict__ W2,
                                              const float* __restrict__ W3,
                                              bf* __restrict__ T1, bf* __restrict__ T2, bf* __restrict__ T3,
                                              int* __restrict__ gcount) {
    int i = blockIdx.x * 256 + threadIdx.x;
    if (i < 256) gcount[i] = 0;
    if (i < NL * F1) {
        int co = i >> 5, ci = i & 31;
        T1[i] = f2b(W1[ci * F1 + co]);
    } else if (i < NL * F1 + F1 * F2) {
        int i2 = i - NL * F1;
        int co = i2 >> 7, ci = i2 & 127;
        T2[i2] = f2b(W2[ci * F2 + co]);
    } else if (i < NL * F1 + F1 * F2 + F2 * F3) {
        int i3 = i - NL * F1 - F1 * F2;
        int co = i3 / 96, ci = i3 - co * 96;
        T3[i3] = f2b(W3[ci * F3 + co]);
    }
}

// ---------------- CSR build: graph-bucket then per-graph sort ----------------
__global__ __launch_bounds__(256) void bucket_k(const int* __restrict__ ei1, const int* __restrict__ ei2,
                                                int* __restrict__ gcount, unsigned* __restrict__ bucket) {
    int side = blockIdx.y;
    const int* src = side ? ei2 : ei1;
    const int* dst = src + NEDGE;
    __shared__ int bc[128], bbase[128], bcur[128];
    int t = threadIdx.x;
    if (t < 128) { bc[t] = 0; bcur[t] = 0; }
    __syncthreads();
    int e0 = blockIdx.x * 1024;
    unsigned lp[4];
    int lg[4];
#pragma unroll
    for (int i = 0; i < 4; i++) {
        int e = e0 + i * 256 + t;
        int s = src[e], d = dst[e];
        int g = d >> 9;
        lp[i] = ((unsigned)s << 9) | (unsigned)(d & 511);
        lg[i] = g;
        atomicAdd(&bc[g], 1);
    }
    __syncthreads();
    if (t < 128 && bc[t] > 0) bbase[t] = atomicAdd(&gcount[side * 128 + t], bc[t]);
    __syncthreads();
#pragma unroll
    for (int i = 0; i < 4; i++) {
        int g = lg[i];
        int pos = bbase[g] + atomicAdd(&bcur[g], 1);
        if (pos < GCAP) bucket[((size_t)side * 128 + g) * GCAP + pos] = lp[i];
    }
}

__global__ void gscan_k(const int* __restrict__ gcount, int* __restrict__ gbase) {
    __shared__ int s[256];
    int t = threadIdx.x;
    int x = gcount[t];
    s[t] = x;
    __syncthreads();
    for (int o = 1; o < 128; o <<= 1) {
        int v = ((t & 127) >= o) ? s[t - o] : 0;
        __syncthreads();
        s[t] += v;
        __syncthreads();
    }
    gbase[t] = (t >> 7) * NEDGE + s[t] - x;
}

// Phase B: one block per graph; CSR built in LDS; edge record 4B: src(u16)|norm(bf16)<<16.
__global__ __launch_bounds__(256) void csr_k(const unsigned* __restrict__ bucket, const int* __restrict__ gcount,
                                             const int* __restrict__ gbase, int* __restrict__ off,
                                             float* __restrict__ dinv, unsigned* __restrict__ ecsr) {
    int side = blockIdx.y, g = blockIdx.x, t = threadIdx.x;
    __shared__ int ncnt[512];
    __shared__ int c2[256];
    __shared__ int cur[512];
    __shared__ float dloc[512];
    ncnt[t] = 0; ncnt[t + 256] = 0;
    __syncthreads();
    int cnt = gcount[side * 128 + g];
    cnt = cnt < GCAP ? cnt : GCAP;
    int base = gbase[side * 128 + g];
    const unsigned* bk = bucket + ((size_t)side * 128 + g) * GCAP;
    for (int i = t; i < cnt; i += 256) atomicAdd(&ncnt[bk[i] & 511], 1);
    __syncthreads();
    int e0 = ncnt[2 * t], e1 = ncnt[2 * t + 1];
    c2[t] = e0 + e1;
    __syncthreads();
    for (int o = 1; o < 256; o <<= 1) {
        int v = (t >= o) ? c2[t - o] : 0;
        __syncthreads();
        c2[t] += v;
        __syncthreads();
    }
    int ex = c2[t] - (e0 + e1);
    cur[2 * t] = ex;
    cur[2 * t + 1] = ex + e0;
    float d0 = rsqrtf((float)e0 + 1.f), d1 = rsqrtf((float)e1 + 1.f);
    dloc[2 * t] = d0; dloc[2 * t + 1] = d1;
    int node0 = g * NPG + 2 * t;
    int* offs = off + side * (NTOT + 1);
    offs[node0] = base + ex;
    offs[node0 + 1] = base + ex + e0;
    *(float2*)(dinv + (size_t)side * NTOT + node0) = make_float2(d0, d1);
    if (g == BGR - 1 && t == 0) offs[NTOT] = (side + 1) * NEDGE;
    __syncthreads();
    for (int i = t; i < cnt; i += 256) {
        unsigned p = bk[i];
        int dl = p & 511;
        int s = p >> 9;
        int pos = atomicAdd(&cur[dl], 1);
        float nm = dloc[s & 511] * dloc[dl];
        ecsr[base + pos] = (unsigned)s | ((unsigned)f2b(nm) << 16);
    }
}

// ---------------- fused layer 1 (both sides via blockIdx.y, global gather) ----------------
__global__ __launch_bounds__(256) void aggemm1_k(const float* __restrict__ x1, const float* __restrict__ x2,
                                                 const int* __restrict__ off, const unsigned* __restrict__ ecsr,
                                                 const float* __restrict__ dinv,
                                                 const bf* __restrict__ wt1, const float* __restrict__ bias,
                                                 bf* __restrict__ outb) {
    int side = blockIdx.y;
    const float* x = side ? x2 : x1;
    const int* offs = off + side * (NTOT + 1);
    const float* dv = dinv + (size_t)side * NTOT;
    bf* out = outb + (size_t)side * NTOT * F1;
    int wave = threadIdx.x >> 6, lane = threadIdx.x & 63;
    int half = lane >> 5, r = lane & 31;
    int row0 = blockIdx.x * 128 + wave * 32;
    int n = row0 + r;
    int g0 = (n >> 9) << 9;   // graph base node (edges are graph-local)
    float z[16];
    float d = dv[n];
    float sc = d * d;
    const float* xr = x + (size_t)n * NL + half * 8;
#pragma unroll
    for (int ks = 0; ks < 2; ks++) {
        float4 v0 = *(const float4*)(xr + ks * 16);
        float4 v1 = *(const float4*)(xr + ks * 16 + 4);
        z[ks * 8 + 0] = v0.x * sc; z[ks * 8 + 1] = v0.y * sc;
        z[ks * 8 + 2] = v0.z * sc; z[ks * 8 + 3] = v0.w * sc;
        z[ks * 8 + 4] = v1.x * sc; z[ks * 8 + 5] = v1.y * sc;
        z[ks * 8 + 6] = v1.z * sc; z[ks * 8 + 7] = v1.w * sc;
    }
    int e0 = offs[n], e1 = offs[n + 1];
    for (int j = e0; j < e1; j++) {
        unsigned en = ecsr[j];
        int s = en & 0xFFFF;
        float w = b2f((bf)(en >> 16));
        const float* xs = x + (size_t)s * NL + half * 8;
#pragma unroll
        for (int ks = 0; ks < 2; ks++) {
            float4 u0 = *(const float4*)(xs + ks * 16);
            float4 u1 = *(const float4*)(xs + ks * 16 + 4);
            z[ks * 8 + 0] += w * u0.x; z[ks * 8 + 1] += w * u0.y;
            z[ks * 8 + 2] += w * u0.z; z[ks * 8 + 3] += w * u0.w;
            z[ks * 8 + 4] += w * u1.x; z[ks * 8 + 5] += w * u1.y;
            z[ks * 8 + 6] += w * u1.z; z[ks * 8 + 7] += w * u1.w;
        }
    }
    (void)g0;
    sv8 a0, a1;
#pragma unroll
    for (int jj = 0; jj < 8; jj++) {
        a0[jj] = (short)f2b(z[jj]);
        a1[jj] = (short)f2b(z[8 + jj]);
    }
#pragma unroll
    for (int nt = 0; nt < F1 / 32; nt++) {
        const bf* Bp = wt1 + (size_t)(nt * 32 + r) * NL + half * 8;
        sv8 b0 = *(const sv8*)(Bp);
        sv8 b1 = *(const sv8*)(Bp + 16);
        fv16 acc;
#pragma unroll
        for (int i = 0; i < 16; i++) acc[i] = 0.f;
        acc = __builtin_amdgcn_mfma_f32_32x32x16_bf16(a0, b0, acc, 0, 0, 0);
        acc = __builtin_amdgcn_mfma_f32_32x32x16_bf16(a1, b1, acc, 0, 0, 0);
        float bv = bias[nt * 32 + r];
#pragma unroll
        for (int i = 0; i < 16; i++) {
            int rr = (i & 3) + 8 * (i >> 2) + 4 * half;
            float v = fmaxf(acc[i] + bv, 0.f);
            out[(size_t)(row0 + rr) * F1 + nt * 32 + r] = f2b(v);
        }
    }
}

// ---------------- MFMA GEMM (both sides via blockIdx.y) ----------------
template <int CIN, int COUT, int BIAS, int RELU>
__global__ __launch_bounds__(256) void gemmm_k(const bf* __restrict__ Xb, const bf* __restrict__ Wt,
                                               const float* __restrict__ bias, bf* __restrict__ outb) {
    int side = blockIdx.y;
    const bf* X = Xb + (size_t)side * NTOT * CIN;
    bf* out = outb + (size_t)side * NTOT * COUT;
    int wave = threadIdx.x >> 6, lane = threadIdx.x & 63;
    int half = lane >> 5, r = lane & 31;
    int row0 = blockIdx.x * 128 + wave * 32;
    const bf* Ap = X + (size_t)(row0 + r) * CIN + half * 8;
    sv8 a[CIN / 16];
#pragma unroll
    for (int k = 0; k < CIN / 16; k++) a[k] = *(const sv8*)(Ap + k * 16);
#pragma unroll
    for (int nt = 0; nt < COUT / 32; nt++) {
        const bf* Bp = Wt + (size_t)(nt * 32 + r) * CIN + half * 8;
        fv16 acc;
#pragma unroll
        for (int i = 0; i < 16; i++) acc[i] = 0.f;
#pragma unroll
        for (int k = 0; k < CIN / 16; k++)
            acc = __builtin_amdgcn_mfma_f32_32x32x16_bf16(a[k], *(const sv8*)(Bp + k * 16), acc, 0, 0, 0);
        float bv = BIAS ? bias[nt * 32 + r] : 0.f;
#pragma unroll
        for (int i = 0; i < 16; i++) {
            int rr = (i & 3) + 8 * (i >> 2) + 4 * half;
            float v = acc[i] + bv;
            if (RELU) v = fmaxf(v, 0.f);
            out[(size_t)(row0 + rr) * COUT + nt * 32 + r] = f2b(v);
        }
    }
}

// ---------------- GCN aggregation (both sides via blockIdx.y, 2x edge unroll) ---------
template <int C, int RELU>
__global__ __launch_bounds__(256) void agg_k(const bf* __restrict__ hinb, const float* __restrict__ bias,
                                             const int* __restrict__ off, const unsigned* __restrict__ ecsr,
                                             const float* __restrict__ dinv, bf* __restrict__ outb) {
    constexpr int C4 = C / 4;
    int side = blockIdx.y;
    const bf* hin = hinb + (size_t)side * NTOT * C;
    bf* out = outb + (size_t)side * NTOT * C;
    const int* offs = off + side * (NTOT + 1);
    int t = blockIdx.x * 256 + threadIdx.x;
    int node = t / C4;
    int c = (t % C4) * 4;
    float d = dinv[(size_t)side * NTOT + node];
    float sc = d * d;
    ushort4 h = *(const ushort4*)(hin + (size_t)node * C + c);
    float ax = b2f(h.x) * sc, ay = b2f(h.y) * sc, az = b2f(h.z) * sc, aw = b2f(h.w) * sc;
    int e0 = offs[node], e1 = offs[node + 1];
    int j = e0;
    for (; j + 2 <= e1; j += 2) {
        unsigned ena = ecsr[j], enb = ecsr[j + 1];
        int sa = ena & 0xFFFF, sb = enb & 0xFFFF;
        float wa = b2f((bf)(ena >> 16)), wb = b2f((bf)(enb >> 16));
        ushort4 ha = *(const ushort4*)(hin + (size_t)sa * C + c);
        ushort4 hb = *(const ushort4*)(hin + (size_t)sb * C + c);
        ax += wa * b2f(ha.x) + wb * b2f(hb.x);
        ay += wa * b2f(ha.y) + wb * b2f(hb.y);
        az += wa * b2f(ha.z) + wb * b2f(hb.z);
        aw += wa * b2f(ha.w) + wb * b2f(hb.w);
    }
    if (j < e1) {
        unsigned en = ecsr[j];
        int s = en & 0xFFFF;
        float w = b2f((bf)(en >> 16));
        ushort4 hs = *(const ushort4*)(hin + (size_t)s * C + c);
        ax += w * b2f(hs.x); ay += w * b2f(hs.y); az += w * b2f(hs.z); aw += w * b2f(hs.w);
    }
    float4 bv = *(const float4*)(bias + c);
    ax += bv.x; ay += bv.y; az += bv.z; aw += bv.w;
    if (RELU) {
        ax = fmaxf(ax, 0.f); ay = fmaxf(ay, 0.f); az = fmaxf(az, 0.f); aw = fmaxf(aw, 0.f);
    }
    ushort4 o;
    o.x = f2b(ax); o.y = f2b(ay); o.z = f2b(az); o.w = f2b(aw);
    *(ushort4*)(out + (size_t)node * C + c) = o;
}

// final agg writes to separate f buffers
template <int C>
__global__ __launch_bounds__(256) void aggf_k(const bf* __restrict__ hinb, const float* __restrict__ bias,
                                              const int* __restrict__ off, const unsigned* __restrict__ ecsr,
                                              const float* __restrict__ dinv,
                                              bf* __restrict__ f1, bf* __restrict__ f2) {
    constexpr int C4 = C / 4;
    int side = blockIdx.y;
    const bf* hin = hinb + (size_t)side * NTOT * C;
    bf* out = side ? f2 : f1;
    const int* offs = off + side * (NTOT + 1);
    int t = blockIdx.x * 256 + threadIdx.x;
    int node = t / C4;
    int c = (t % C4) * 4;
    float d = dinv[(size_t)side * NTOT + node];
    float sc = d * d;
    ushort4 h = *(const ushort4*)(hin + (size_t)node * C + c);
    float ax = b2f(h.x) * sc, ay = b2f(h.y) * sc, az = b2f(h.z) * sc, aw = b2f(h.w) * sc;
    int e0 = offs[node], e1 = offs[node + 1];
    int j = e0;
    for (; j + 2 <= e1; j += 2) {
        unsigned ena = ecsr[j], enb = ecsr[j + 1];
        int sa = ena & 0xFFFF, sb = enb & 0xFFFF;
        float wa = b2f((bf)(ena >> 16)), wb = b2f((bf)(enb >> 16));
        ushort4 ha = *(const ushort4*)(hin + (size_t)sa * C + c);
        ushort4 hb = *(const ushort4*)(hin + (size_t)sb * C + c);
        ax += wa * b2f(ha.x) + wb * b2f(hb.x);
        ay += wa * b2f(ha.y) + wb * b2f(hb.y);
        az += wa * b2f(ha.z) + wb * b2f(hb.z);
        aw += wa * b2f(ha.w) + wb * b2f(hb.w);
    }
    if (j < e1) {
        unsigned en = ecsr[j];
        int s = en & 0xFFFF;
        float w = b2f((bf)(en >> 16));
        ushort4 hs = *(const ushort4*)(hin + (size_t)s * C + c);
        ax += w * b2f(hs.x); ay += w * b2f(hs.y); az += w * b2f(hs.z); aw += w * b2f(hs.w);
    }
    float4 bv = *(const float4*)(bias + c);
    ax += bv.x; ay += bv.y; az += bv.z; aw += bv.w;
    ushort4 o;
    o.x = f2b(ax); o.y = f2b(ay); o.z = f2b(az); o.w = f2b(aw);
    *(ushort4*)(out + (size_t)node * C + c) = o;
}

// ---------------- sim tile core ----------------
__device__ __forceinline__ void sim_tile(const bf* __restrict__ f1, const bf* __restrict__ f2,
                                         int g, int mt, int wave, int lane, fv16 acc[4]) {
    int half = lane >> 5, r = lane & 31;
    const bf* Ap = f1 + ((size_t)g * NPG + mt * 32 + r) * F3 + half * 8;
    sv8 a0 = *(const sv8*)(Ap +  0);
    sv8 a1 = *(const sv8*)(Ap + 16);
    sv8 a2 = *(const sv8*)(Ap + 32);
    sv8 a3 = *(const sv8*)(Ap + 48);
#pragma unroll
    for (int j = 0; j < 4; j++) {
        int nt = j * 4 + wave;
        const bf* Bp = f2 + ((size_t)g * NPG + nt * 32 + r) * F3 + half * 8;
#pragma unroll
        for (int i = 0; i < 16; i++) acc[j][i] = 0.f;
        acc[j] = __builtin_amdgcn_mfma_f32_32x32x16_bf16(a0, *(const sv8*)(Bp +  0), acc[j], 0, 0, 0);
        acc[j] = __builtin_amdgcn_mfma_f32_32x32x16_bf16(a1, *(const sv8*)(Bp + 16), acc[j], 0, 0, 0);
        acc[j] = __builtin_amdgcn_mfma_f32_32x32x16_bf16(a2, *(const sv8*)(Bp + 32), acc[j], 0, 0, 0);
        acc[j] = __builtin_amdgcn_mfma_f32_32x32x16_bf16(a3, *(const sv8*)(Bp + 48), acc[j], 0, 0, 0);
    }
}

// ---------------- combo: simm (blocks 0..2047) + meanp (blocks 2048..4095) ----------------
__global__ __launch_bounds__(256) void simmean_k(const bf* __restrict__ f1, const bf* __restrict__ f2,
                                                 float* __restrict__ statmin, float* __restrict__ statmax,
                                                 float* __restrict__ meanp) {
    __shared__ float red[256];
    int bid = blockIdx.x;
    int t = threadIdx.x, wave = t >> 6, lane = t & 63;
    if (bid < 2048) {
        int g = bid >> 4, mt = bid & 15;
        fv16 acc[4];
        sim_tile(f1, f2, g, mt, wave, lane, acc);
        float mn = 1e30f, mx = -1e30f;
#pragma unroll
        for (int j = 0; j < 4; j++)
#pragma unroll
            for (int i = 0; i < 16; i++) {
                mn = fminf(mn, acc[j][i]);
                mx = fmaxf(mx, acc[j][i]);
            }
        for (int o = 32; o; o >>= 1) {
            mn = fminf(mn, __shfl_down(mn, o));
            mx = fmaxf(mx, __shfl_down(mx, o));
        }
        if (lane == 0) { red[wave] = mn; red[4 + wave] = mx; }
        __syncthreads();
        if (t == 0) {
            statmin[g * 16 + mt] = fminf(fminf(red[0], red[1]), fminf(red[2], red[3]));
            statmax[g * 16 + mt] = fmaxf(fmaxf(red[4], red[5]), fmaxf(red[6], red[7]));
        }
    } else {
        int idx = bid - 2048;
        int side = idx >> 10, rem = idx & 1023;
        int ch = rem >> 7, g = rem & 127;
        const bf* xp = (side ? f2 : f1) + ((size_t)g * NPG + ch * 64) * F3;
        int f = t & 63;
        float m = 0.f;
#pragma unroll 4
        for (int i = 0; i < 16; i++) m += b2f(xp[(size_t)(wave * 16 + i) * F3 + f]);
        red[t] = m;
        __syncthreads();
        if (t < 64) meanp[(((size_t)side * BGR + g) * 8 + ch) * 64 + t] =
            red[t] + red[64 + t] + red[128 + t] + red[192 + t];
    }
}

// ---------------- combo: simh (blocks 0..2047) + ctx (blocks 2048..2303) ----------------
__global__ __launch_bounds__(256) void simhctx_k(const bf* __restrict__ f1, const bf* __restrict__ f2,
                                                 const float* __restrict__ statmin, const float* __restrict__ statmax,
                                                 int* __restrict__ hist_p,
                                                 const float* __restrict__ meanp, const float* __restrict__ Watt,
                                                 float* __restrict__ ctxb) {
    __shared__ int ph[256 * 17];
    __shared__ int pr[256];
    int bid = blockIdx.x;
    int t = threadIdx.x, wave = t >> 6, lane = t & 63;
    if (bid < 2048) {
        int g = bid >> 4, mt = bid & 15;
#pragma unroll
        for (int b = 0; b < BINS; b++) ph[t * 17 + b] = 0;
        float pm = (lane < 16) ? statmin[g * 16 + lane] : 1e30f;
        float px = (lane < 16) ? statmax[g * 16 + lane] : -1e30f;
        for (int o = 8; o; o >>= 1) {
            pm = fminf(pm, __shfl_down(pm, o));
            px = fmaxf(px, __shfl_down(px, o));
        }
        float vmin = sigm(__shfl(pm, 0));
        float vmax = sigm(__shfl(px, 0));
        float width = (vmax - vmin) / (float)BINS;
        float inv = 1.0f / (width > 0.f ? width : 1.0f);
        fv16 acc[4];
        sim_tile(f1, f2, g, mt, wave, lane, acc);
#pragma unroll
        for (int j = 0; j < 4; j++)
#pragma unroll
            for (int i = 0; i < 16; i++) {
                float v = sigm(acc[j][i]);
                int bi = (int)floorf((v - vmin) * inv);
                bi = bi < 0 ? 0 : (bi > BINS - 1 ? BINS - 1 : bi);
                ph[t * 17 + bi] += 1;
            }
        __syncthreads();
        {
            int grp = t >> 4, bin = t & 15;
            int s = 0;
#pragma unroll
            for (int j = 0; j < 16; j++) s += ph[(grp * 16 + j) * 17 + bin];
            pr[t] = s;
        }
        __syncthreads();
        if (t < BINS) {
            int tot = 0;
#pragma unroll
            for (int j = 0; j < 16; j++) tot += pr[j * 16 + t];
            hist_p[((size_t)g * 16 + mt) * BINS + t] = tot;
        }
    } else {
        int idx = bid - 2048;
        int side = idx >> 7, g = idx & 127;
        float* sm = (float*)pr;
        if (t < 64) {
            float m = 0.f;
#pragma unroll
            for (int ch = 0; ch < 8; ch++) m += meanp[(((size_t)side * BGR + g) * 8 + ch) * 64 + t];
            sm[t] = m * (1.0f / (float)NPG);
        }
        __syncthreads();
        if (t < 64) {
            float acc = 0.f;
#pragma unroll 8
            for (int i = 0; i < F3; i++) acc += sm[i] * Watt[i * F3 + t];
            ctxb[((size_t)side * BGR + g) * F3 + t] = tanhf(acc);
        }
    }
}

// coef + weighted partial pool; grid (BGR, 8, 2)
__global__ __launch_bounds__(256) void cpool_k(const bf* __restrict__ f1, const bf* __restrict__ f2,
                                               const float* __restrict__ ctxb, float* __restrict__ poolp) {
    int g = blockIdx.x, ch = blockIdx.y, side = blockIdx.z;
    const bf* xp = (side ? f2 : f1) + ((size_t)g * NPG + ch * 64) * F3;
    int t = threadIdx.x, w = t >> 6, f = t & 63;
    float cx = ctxb[((size_t)side * BGR + g) * F3 + f];
    float acc = 0.f;
    for (int i = 0; i < 16; i++) {
        float v = b2f(xp[(size_t)(w * 16 + i) * F3 + f]);
        float d = v * cx;
#pragma unroll
        for (int o = 1; o < 64; o <<= 1) d += __shfl_xor(d, o);
        acc += sigm(d) * v;
    }
    __shared__ float red[256];
    red[t] = acc;
    __syncthreads();
    if (t < 64) poolp[(((size_t)side * BGR + g) * 8 + ch) * 64 + t] =
        red[t] + red[64 + t] + red[128 + t] + red[192 + t];
}

// ---------------- tensor network + tail MLP ----------------
__global__ __launch_bounds__(256) void final_k(const float* __restrict__ poolp,
                                               const float* __restrict__ Wt, const float* __restrict__ Wtb,
                                               const float* __restrict__ tb, const int* __restrict__ hist_p,
                                               const float* __restrict__ W1, const float* __restrict__ b1,
                                               const float* __restrict__ Ws, const float* __restrict__ bs,
                                               float* __restrict__ out) {
    int b = blockIdx.x, t = threadIdx.x;
    __shared__ float cat[128];
    __shared__ float sacc[256];
    __shared__ float feat[32];
    __shared__ float hb[32];
    if (t < 128) {
        int side = t >> 6, f = t & 63;
        float s = 0.f;
#pragma unroll
        for (int ch = 0; ch < 8; ch++) s += poolp[(((size_t)side * BGR + b) * 8 + ch) * 64 + f];
        cat[t] = s;
    }
    __syncthreads();
    int k = t & 15, c = t >> 4;
    float acc = 0.f;
    for (int q = 0; q < 256; q++) {
        int ij = c * 256 + q;
        int i = ij >> 6, j = ij & 63;
        acc += cat[i] * cat[64 + j] * Wt[ij * KT + k];
    }
    sacc[t] = acc;
    __syncthreads();
    if (t < KT) {
        float sc = 0.f;
        for (int c2 = 0; c2 < 16; c2++) sc += sacc[c2 * 16 + t];
        float bt = 0.f;
        for (int i = 0; i < 128; i++) bt += cat[i] * Wtb[t * 128 + i];
        float tv = sc + bt + tb[t];
        feat[t] = tv > 0.f ? tv : 0.f;
        int hsum = 0;
#pragma unroll
        for (int j = 0; j < 16; j++) hsum += hist_p[((size_t)b * 16 + j) * BINS + t];
        feat[KT + t] = (float)hsum * (1.0f / (float)(NPG * NPG));
    }
    __syncthreads();
    if (t < BN) {
        float a = 0.f;
        for (int i = 0; i < KT + BINS; i++) a += feat[i] * W1[i * BN + t];
        a += b1[t];
        hb[t] = a > 0.f ? a : 0.f;
    }
    __syncthreads();
    if (t == 0) {
        float s = bs[0];
        for (int j = 0; j < BN; j++) s += hb[j] * Ws[j];
        out[b] = sigm(s);
    }
}

// ---------------- launch ----------------
extern "C" void kernel_launch(void* const* d_in, const int* in_sizes, int n_in,
                              void* d_out, int out_size, void* d_ws, size_t ws_size,
                              hipStream_t stream) {
    const float* x1   = (const float*)d_in[0];
    const float* x2   = (const float*)d_in[1];
    const int*   ei1  = (const int*)d_in[2];
    const int*   ei2  = (const int*)d_in[3];
    const float* Wc1  = (const float*)d_in[6];
    const float* bc1  = (const float*)d_in[7];
    const float* Wc2  = (const float*)d_in[8];
    const float* bc2  = (const float*)d_in[9];
    const float* Wc3  = (const float*)d_in[10];
    const float* bc3  = (const float*)d_in[11];
    const float* Watt = (const float*)d_in[12];
    const float* Wt   = (const float*)d_in[13];
    const float* Wtb  = (const float*)d_in[14];
    const float* tb   = (const float*)d_in[15];
    const float* W1   = (const float*)d_in[16];
    const float* b1   = (const float*)d_in[17];
    const float* Ws   = (const float*)d_in[18];
    const float* bs   = (const float*)d_in[19];
    float* out = (float*)d_out;

    // ---- workspace layout (~100 MB) ----
    char* wsb = (char*)d_ws;
    size_t o = 0;
    auto alloc = [&](size_t bytes) -> void* {
        void* p = wsb + o;
        o = (o + bytes + 255) & ~(size_t)255;
        return p;
    };
    bf* f1b  = (bf*)alloc((size_t)NTOT * F3 * 2);     //  8 MB
    bf* f2b  = (bf*)alloc((size_t)NTOT * F3 * 2);     //  8 MB
    bf* X    = (bf*)alloc((size_t)2 * NTOT * F1 * 2); // 32 MB (both sides)
    bf* Y    = (bf*)alloc((size_t)2 * NTOT * F2 * 2); // 24 MB (both sides)
    int* off   = (int*)alloc((size_t)2 * (NTOT + 1) * 4);
    unsigned* ecsr = (unsigned*)alloc((size_t)2 * NEDGE * 4);        // 4 MB packed src|norm
    unsigned* bucket = (unsigned*)alloc((size_t)2 * 128 * GCAP * 4); // 6.3 MB
    int* gcount = (int*)alloc(256 * 4);
    int* gbase  = (int*)alloc(256 * 4);
    float* dinv = (float*)alloc((size_t)2 * NTOT * 4);
    float* statmin = (float*)alloc((size_t)BGR * 16 * 4);
    float* statmax = (float*)alloc((size_t)BGR * 16 * 4);
    int* hist_p = (int*)alloc((size_t)BGR * 16 * BINS * 4);
    float* meanp = (float*)alloc((size_t)2 * BGR * 8 * 64 * 4);
    float* ctx   = (float*)alloc((size_t)2 * BGR * F3 * 4);
    float* poolp = (float*)alloc((size_t)2 * BGR * 8 * 64 * 4);
    bf* wt1 = (bf*)alloc((size_t)NL * F1 * 2);   // Wt1[F1][NL]
    bf* wt2 = (bf*)alloc((size_t)F1 * F2 * 2);   // Wt2[F2][F1]
    bf* wt3 = (bf*)alloc((size_t)F2 * F3 * 2);   // Wt3[F3][F2]
    (void)ws_size; (void)in_sizes; (void)n_in; (void)out_size;

    // init: zero gcount + weight transpose (single dispatch)
    init_k<<<(NL * F1 + F1 * F2 + F2 * F3 + 255) / 256, 256, 0, stream>>>(Wc1, Wc2, Wc3, wt1, wt2, wt3, gcount);

    // ---- CSR build: bucket by graph, scan, per-graph sort ----
    bucket_k<<<dim3(NEDGE / 1024, 2), 256, 0, stream>>>(ei1, ei2, gcount, bucket);
    gscan_k<<<1, 256, 0, stream>>>(gcount, gbase);
    csr_k<<<dim3(BGR, 2), 256, 0, stream>>>(bucket, gcount, gbase, off, dinv, ecsr);

    // ---- GCN stack: both sides batched per layer; global L2 gathers (high TLP) ----
    aggemm1_k<<<dim3(NTOT / 128, 2), 256, 0, stream>>>(x1, x2, off, ecsr, dinv, wt1, bc1, X);
    gemmm_k<F1, F2, 0, 0><<<dim3(NTOT / 128, 2), 256, 0, stream>>>(X, wt2, nullptr, Y);
    agg_k<F2, 1><<<dim3((NTOT * (F2 / 4)) / 256, 2), 256, 0, stream>>>(Y, bc2, off, ecsr, dinv, X);
    gemmm_k<F2, F3, 0, 0><<<dim3(NTOT / 128, 2), 256, 0, stream>>>(X, wt3, nullptr, Y);
    aggf_k<F3><<<dim3((NTOT * (F3 / 4)) / 256, 2), 256, 0, stream>>>(Y, bc3, off, ecsr, dinv, f1b, f2b);

    // ---- sim minmax + mean partials (one dispatch) ----
    simmean_k<<<4096, 256, 0, stream>>>(f1b, f2b, statmin, statmax, meanp);
    // ---- sim hist + ctx (one dispatch) ----
    simhctx_k<<<2048 + 256, 256, 0, stream>>>(f1b, f2b, statmin, statmax, hist_p, meanp, Watt, ctx);
    // ---- coef + weighted pool partials ----
    cpool_k<<<dim3(BGR, 8, 2), 256, 0, stream>>>(f1b, f2b, ctx, poolp);

    // ---- tensor network + MLP tail ----
    final_k<<<BGR, 256, 0, stream>>>(poolp, Wt, Wtb, tb, hist_p, W1, b1, Ws, bs, out);
}

// Round 12
// 339.728 us; speedup vs baseline: 1.0853x; 1.0321x over previous
//
#include <hip/hip_runtime.h>
#include <math.h>

#define NTOT  65536
#define NEDGE 524288
#define BGR   128
#define NPG   512
#define NL    32
#define F1    128
#define F2    96
#define F3    64
#define KT    16
#define BINS  16
#define BN    32
#define GCAP  6144   // per-graph edge bucket capacity (mean 4096, +32 sigma)

typedef unsigned short bf;
typedef __attribute__((ext_vector_type(8))) short sv8;    // 8 bf16 fragment (4 VGPRs)
typedef __attribute__((ext_vector_type(16))) float fv16;  // 32x32 mfma accumulator

// ---------------- helpers ----------------
__device__ __forceinline__ float b2f(bf v) { return __uint_as_float(((unsigned)v) << 16); }
__device__ __forceinline__ bf f2b(float f) {
    unsigned u = __float_as_uint(f);
    return (bf)((u + 0x7FFF + ((u >> 16) & 1)) >> 16);  // RNE
}
__device__ __forceinline__ float sigm(float x) { return 1.f / (1.f + expf(-x)); }

// ---------------- init: zero gcount + transpose/convert all weights ----------------
__global__ __launch_bounds__(256) void init_k(const float* __restrict__ W1, const float* __restrict__ W2,
                                              const float* __restrict__ W3,
                                              bf* __restrict__ T1, bf* __restrict__ T2, bf* __restrict__ T3,
                                              int* __restrict__ gcount) {
    int i = blockIdx.x * 256 + threadIdx.x;
    if (i < 256) gcount[i] = 0;
    if (i < NL * F1) {
        int co = i >> 5, ci = i & 31;
        T1[i] = f2b(W1[ci * F1 + co]);
    } else if (i < NL * F1 + F1 * F2) {
        int i2 = i - NL * F1;
        int co = i2 >> 7, ci = i2 & 127;
        T2[i2] = f2b(W2[ci * F2 + co]);
    } else if (i < NL * F1 + F1 * F2 + F2 * F3) {
        int i3 = i - NL * F1 - F1 * F2;
        int co = i3 / 96, ci = i3 - co * 96;
        T3[i3] = f2b(W3[ci * F3 + co]);
    }
}

// ---------------- CSR build: graph-bucket then per-graph sort ----------------
__global__ __launch_bounds__(256) void bucket_k(const int* __restrict__ ei1, const int* __restrict__ ei2,
                                                int* __restrict__ gcount, unsigned* __restrict__ bucket) {
    int side = blockIdx.y;
    const int* src = side ? ei2 : ei1;
    const int* dst = src + NEDGE;
    __shared__ int bc[128], bbase[128], bcur[128];
    int t = threadIdx.x;
    if (t < 128) { bc[t] = 0; bcur[t] = 0; }
    __syncthreads();
    int e0 = blockIdx.x * 1024;
    unsigned lp[4];
    int lg[4];
#pragma unroll
    for (int i = 0; i < 4; i++) {
        int e = e0 + i * 256 + t;
        int s = src[e], d = dst[e];
        int g = d >> 9;
        lp[i] = ((unsigned)s << 9) | (unsigned)(d & 511);
        lg[i] = g;
        atomicAdd(&bc[g], 1);
    }
    __syncthreads();
    if (t < 128 && bc[t] > 0) bbase[t] = atomicAdd(&gcount[side * 128 + t], bc[t]);
    __syncthreads();
#pragma unroll
    for (int i = 0; i < 4; i++) {
        int g = lg[i];
        int pos = bbase[g] + atomicAdd(&bcur[g], 1);
        if (pos < GCAP) bucket[((size_t)side * 128 + g) * GCAP + pos] = lp[i];
    }
}

// Phase B: one block per graph; CSR built in LDS; in-block scan of per-graph counts
// replaces the old gscan_k dispatch. Edge record 4B: src(u16)|norm(bf16)<<16.
__global__ __launch_bounds__(256) void csr_k(const unsigned* __restrict__ bucket, const int* __restrict__ gcount,
                                             int* __restrict__ off, float* __restrict__ dinv,
                                             unsigned* __restrict__ ecsr) {
    int side = blockIdx.y, g = blockIdx.x, t = threadIdx.x;
    __shared__ int ncnt[512];
    __shared__ int c2[256];
    __shared__ int cur[512];
    __shared__ float dloc[512];
    __shared__ int gs[128];
    ncnt[t] = 0; ncnt[t + 256] = 0;
    if (t < 128) gs[t] = gcount[side * 128 + t];
    __syncthreads();
    // inclusive scan of the 128 per-graph counts
    for (int o = 1; o < 128; o <<= 1) {
        int v = (t >= o && t < 128) ? gs[t - o] : 0;
        __syncthreads();
        if (t < 128) gs[t] += v;
        __syncthreads();
    }
    int cnt = gcount[side * 128 + g];
    cnt = cnt < GCAP ? cnt : GCAP;
    int base = side * NEDGE + (g > 0 ? gs[g - 1] : 0);
    const unsigned* bk = bucket + ((size_t)side * 128 + g) * GCAP;
    for (int i = t; i < cnt; i += 256) atomicAdd(&ncnt[bk[i] & 511], 1);
    __syncthreads();
    int e0 = ncnt[2 * t], e1 = ncnt[2 * t + 1];
    c2[t] = e0 + e1;
    __syncthreads();
    for (int o = 1; o < 256; o <<= 1) {
        int v = (t >= o) ? c2[t - o] : 0;
        __syncthreads();
        c2[t] += v;
        __syncthreads();
    }
    int ex = c2[t] - (e0 + e1);
    cur[2 * t] = ex;
    cur[2 * t + 1] = ex + e0;
    float d0 = rsqrtf((float)e0 + 1.f), d1 = rsqrtf((float)e1 + 1.f);
    dloc[2 * t] = d0; dloc[2 * t + 1] = d1;
    int node0 = g * NPG + 2 * t;
    int* offs = off + side * (NTOT + 1);
    offs[node0] = base + ex;
    offs[node0 + 1] = base + ex + e0;
    *(float2*)(dinv + (size_t)side * NTOT + node0) = make_float2(d0, d1);
    if (g == BGR - 1 && t == 0) offs[NTOT] = (side + 1) * NEDGE;
    __syncthreads();
    for (int i = t; i < cnt; i += 256) {
        unsigned p = bk[i];
        int dl = p & 511;
        int s = p >> 9;
        int pos = atomicAdd(&cur[dl], 1);
        float nm = dloc[s & 511] * dloc[dl];
        ecsr[base + pos] = (unsigned)s | ((unsigned)f2b(nm) << 16);
    }
}

// ---------------- fused layers 1+2: t2 = relu((A_hat x) W1 + b1) W2 ----------------
// Row-local fusion: each wave's MFMA1 C-tile covers exactly its own 32 rows, so the
// C-layout -> A-fragment transform goes through a wave-private LDS region (no barrier).
#define HSTR 136   // 128 + 8 bf16 pad: rows 16B-aligned, bank stride 4
__global__ __launch_bounds__(256) void aggemm12_k(const float* __restrict__ x1, const float* __restrict__ x2,
                                                  const int* __restrict__ off, const unsigned* __restrict__ ecsr,
                                                  const float* __restrict__ dinv,
                                                  const bf* __restrict__ wt1, const float* __restrict__ bc1,
                                                  const bf* __restrict__ wt2, bf* __restrict__ Yb) {
    __shared__ bf Hs[128 * HSTR];   // 34816 B
    int side = blockIdx.y;
    const float* x = side ? x2 : x1;
    const int* offs = off + side * (NTOT + 1);
    const float* dv = dinv + (size_t)side * NTOT;
    bf* Y = Yb + (size_t)side * NTOT * F2;
    int wave = threadIdx.x >> 6, lane = threadIdx.x & 63;
    int half = lane >> 5, r = lane & 31;
    int row0 = blockIdx.x * 128 + wave * 32;
    int n = row0 + r;
    // ---- phase 1: layer-1 aggregation over fp32 x (global L2 gather) ----
    float z[16];
    float d = dv[n];
    float sc = d * d;
    const float* xr = x + (size_t)n * NL + half * 8;
#pragma unroll
    for (int ks = 0; ks < 2; ks++) {
        float4 v0 = *(const float4*)(xr + ks * 16);
        float4 v1 = *(const float4*)(xr + ks * 16 + 4);
        z[ks * 8 + 0] = v0.x * sc; z[ks * 8 + 1] = v0.y * sc;
        z[ks * 8 + 2] = v0.z * sc; z[ks * 8 + 3] = v0.w * sc;
        z[ks * 8 + 4] = v1.x * sc; z[ks * 8 + 5] = v1.y * sc;
        z[ks * 8 + 6] = v1.z * sc; z[ks * 8 + 7] = v1.w * sc;
    }
    int e0 = offs[n], e1 = offs[n + 1];
    for (int j = e0; j < e1; j++) {
        unsigned en = ecsr[j];
        int s = en & 0xFFFF;
        float w = b2f((bf)(en >> 16));
        const float* xs = x + (size_t)s * NL + half * 8;
#pragma unroll
        for (int ks = 0; ks < 2; ks++) {
            float4 u0 = *(const float4*)(xs + ks * 16);
            float4 u1 = *(const float4*)(xs + ks * 16 + 4);
            z[ks * 8 + 0] += w * u0.x; z[ks * 8 + 1] += w * u0.y;
            z[ks * 8 + 2] += w * u0.z; z[ks * 8 + 3] += w * u0.w;
            z[ks * 8 + 4] += w * u1.x; z[ks * 8 + 5] += w * u1.y;
            z[ks * 8 + 6] += w * u1.z; z[ks * 8 + 7] += w * u1.w;
        }
    }
    sv8 a0, a1;
#pragma unroll
    for (int jj = 0; jj < 8; jj++) {
        a0[jj] = (short)f2b(z[jj]);
        a1[jj] = (short)f2b(z[8 + jj]);
    }
    // ---- MFMA1 + bias + relu -> wave-private LDS tile (C layout) ----
#pragma unroll
    for (int nt = 0; nt < F1 / 32; nt++) {
        const bf* Bp = wt1 + (size_t)(nt * 32 + r) * NL + half * 8;
        sv8 b0 = *(const sv8*)(Bp);
        sv8 b1 = *(const sv8*)(Bp + 16);
        fv16 acc;
#pragma unroll
        for (int i = 0; i < 16; i++) acc[i] = 0.f;
        acc = __builtin_amdgcn_mfma_f32_32x32x16_bf16(a0, b0, acc, 0, 0, 0);
        acc = __builtin_amdgcn_mfma_f32_32x32x16_bf16(a1, b1, acc, 0, 0, 0);
        float bv = bc1[nt * 32 + r];
#pragma unroll
        for (int i = 0; i < 16; i++) {
            int rr = (i & 3) + 8 * (i >> 2) + 4 * half;
            Hs[(wave * 32 + rr) * HSTR + nt * 32 + r] = f2b(fmaxf(acc[i] + bv, 0.f));
        }
    }
    // wave-private rows: no __syncthreads needed (compiler inserts lgkmcnt waits)
    // ---- phase 2: t2 = h1 @ Wt2 -> Y (A-fragments from LDS) ----
    sv8 a[8];
#pragma unroll
    for (int k = 0; k < 8; k++)
        a[k] = *(const sv8*)&Hs[(wave * 32 + r) * HSTR + k * 16 + half * 8];
#pragma unroll
    for (int nt = 0; nt < F2 / 32; nt++) {
        const bf* Bp = wt2 + (size_t)(nt * 32 + r) * F1 + half * 8;
        fv16 acc;
#pragma unroll
        for (int i = 0; i < 16; i++) acc[i] = 0.f;
#pragma unroll
        for (int k = 0; k < 8; k++)
            acc = __builtin_amdgcn_mfma_f32_32x32x16_bf16(a[k], *(const sv8*)(Bp + k * 16), acc, 0, 0, 0);
#pragma unroll
        for (int i = 0; i < 16; i++) {
            int rr = (i & 3) + 8 * (i >> 2) + 4 * half;
            Y[(size_t)(row0 + rr) * F2 + nt * 32 + r] = f2b(acc[i]);
        }
    }
}

// ---------------- MFMA GEMM (both sides via blockIdx.y) ----------------
template <int CIN, int COUT, int BIAS, int RELU>
__global__ __launch_bounds__(256) void gemmm_k(const bf* __restrict__ Xb, const bf* __restrict__ Wt,
                                               const float* __restrict__ bias, bf* __restrict__ outb) {
    int side = blockIdx.y;
    const bf* X = Xb + (size_t)side * NTOT * CIN;
    bf* out = outb + (size_t)side * NTOT * COUT;
    int wave = threadIdx.x >> 6, lane = threadIdx.x & 63;
    int half = lane >> 5, r = lane & 31;
    int row0 = blockIdx.x * 128 + wave * 32;
    const bf* Ap = X + (size_t)(row0 + r) * CIN + half * 8;
    sv8 a[CIN / 16];
#pragma unroll
    for (int k = 0; k < CIN / 16; k++) a[k] = *(const sv8*)(Ap + k * 16);
#pragma unroll
    for (int nt = 0; nt < COUT / 32; nt++) {
        const bf* Bp = Wt + (size_t)(nt * 32 + r) * CIN + half * 8;
        fv16 acc;
#pragma unroll
        for (int i = 0; i < 16; i++) acc[i] = 0.f;
#pragma unroll
        for (int k = 0; k < CIN / 16; k++)
            acc = __builtin_amdgcn_mfma_f32_32x32x16_bf16(a[k], *(const sv8*)(Bp + k * 16), acc, 0, 0, 0);
        float bv = BIAS ? bias[nt * 32 + r] : 0.f;
#pragma unroll
        for (int i = 0; i < 16; i++) {
            int rr = (i & 3) + 8 * (i >> 2) + 4 * half;
            float v = acc[i] + bv;
            if (RELU) v = fmaxf(v, 0.f);
            out[(size_t)(row0 + rr) * COUT + nt * 32 + r] = f2b(v);
        }
    }
}

// ---------------- GCN aggregation (both sides via blockIdx.y, 2x edge unroll) ---------
template <int C, int RELU>
__global__ __launch_bounds__(256) void agg_k(const bf* __restrict__ hinb, const float* __restrict__ bias,
                                             const int* __restrict__ off, const unsigned* __restrict__ ecsr,
                                             const float* __restrict__ dinv, bf* __restrict__ outb) {
    constexpr int C4 = C / 4;
    int side = blockIdx.y;
    const bf* hin = hinb + (size_t)side * NTOT * C;
    bf* out = outb + (size_t)side * NTOT * C;
    const int* offs = off + side * (NTOT + 1);
    int t = blockIdx.x * 256 + threadIdx.x;
    int node = t / C4;
    int c = (t % C4) * 4;
    float d = dinv[(size_t)side * NTOT + node];
    float sc = d * d;
    ushort4 h = *(const ushort4*)(hin + (size_t)node * C + c);
    float ax = b2f(h.x) * sc, ay = b2f(h.y) * sc, az = b2f(h.z) * sc, aw = b2f(h.w) * sc;
    int e0 = offs[node], e1 = offs[node + 1];
    int j = e0;
    for (; j + 2 <= e1; j += 2) {
        unsigned ena = ecsr[j], enb = ecsr[j + 1];
        int sa = ena & 0xFFFF, sb = enb & 0xFFFF;
        float wa = b2f((bf)(ena >> 16)), wb = b2f((bf)(enb >> 16));
        ushort4 ha = *(const ushort4*)(hin + (size_t)sa * C + c);
        ushort4 hb = *(const ushort4*)(hin + (size_t)sb * C + c);
        ax += wa * b2f(ha.x) + wb * b2f(hb.x);
        ay += wa * b2f(ha.y) + wb * b2f(hb.y);
        az += wa * b2f(ha.z) + wb * b2f(hb.z);
        aw += wa * b2f(ha.w) + wb * b2f(hb.w);
    }
    if (j < e1) {
        unsigned en = ecsr[j];
        int s = en & 0xFFFF;
        float w = b2f((bf)(en >> 16));
        ushort4 hs = *(const ushort4*)(hin + (size_t)s * C + c);
        ax += w * b2f(hs.x); ay += w * b2f(hs.y); az += w * b2f(hs.z); aw += w * b2f(hs.w);
    }
    float4 bv = *(const float4*)(bias + c);
    ax += bv.x; ay += bv.y; az += bv.z; aw += bv.w;
    if (RELU) {
        ax = fmaxf(ax, 0.f); ay = fmaxf(ay, 0.f); az = fmaxf(az, 0.f); aw = fmaxf(aw, 0.f);
    }
    ushort4 o;
    o.x = f2b(ax); o.y = f2b(ay); o.z = f2b(az); o.w = f2b(aw);
    *(ushort4*)(out + (size_t)node * C + c) = o;
}

// final agg writes to separate f buffers
template <int C>
__global__ __launch_bounds__(256) void aggf_k(const bf* __restrict__ hinb, const float* __restrict__ bias,
                                              const int* __restrict__ off, const unsigned* __restrict__ ecsr,
                                              const float* __restrict__ dinv,
                                              bf* __restrict__ f1, bf* __restrict__ f2) {
    constexpr int C4 = C / 4;
    int side = blockIdx.y;
    const bf* hin = hinb + (size_t)side * NTOT * C;
    bf* out = side ? f2 : f1;
    const int* offs = off + side * (NTOT + 1);
    int t = blockIdx.x * 256 + threadIdx.x;
    int node = t / C4;
    int c = (t % C4) * 4;
    float d = dinv[(size_t)side * NTOT + node];
    float sc = d * d;
    ushort4 h = *(const ushort4*)(hin + (size_t)node * C + c);
    float ax = b2f(h.x) * sc, ay = b2f(h.y) * sc, az = b2f(h.z) * sc, aw = b2f(h.w) * sc;
    int e0 = offs[node], e1 = offs[node + 1];
    int j = e0;
    for (; j + 2 <= e1; j += 2) {
        unsigned ena = ecsr[j], enb = ecsr[j + 1];
        int sa = ena & 0xFFFF, sb = enb & 0xFFFF;
        float wa = b2f((bf)(ena >> 16)), wb = b2f((bf)(enb >> 16));
        ushort4 ha = *(const ushort4*)(hin + (size_t)sa * C + c);
        ushort4 hb = *(const ushort4*)(hin + (size_t)sb * C + c);
        ax += wa * b2f(ha.x) + wb * b2f(hb.x);
        ay += wa * b2f(ha.y) + wb * b2f(hb.y);
        az += wa * b2f(ha.z) + wb * b2f(hb.z);
        aw += wa * b2f(ha.w) + wb * b2f(hb.w);
    }
    if (j < e1) {
        unsigned en = ecsr[j];
        int s = en & 0xFFFF;
        float w = b2f((bf)(en >> 16));
        ushort4 hs = *(const ushort4*)(hin + (size_t)s * C + c);
        ax += w * b2f(hs.x); ay += w * b2f(hs.y); az += w * b2f(hs.z); aw += w * b2f(hs.w);
    }
    float4 bv = *(const float4*)(bias + c);
    ax += bv.x; ay += bv.y; az += bv.z; aw += bv.w;
    ushort4 o;
    o.x = f2b(ax); o.y = f2b(ay); o.z = f2b(az); o.w = f2b(aw);
    *(ushort4*)(out + (size_t)node * C + c) = o;
}

// ---------------- sim tile core ----------------
__device__ __forceinline__ void sim_tile(const bf* __restrict__ f1, const bf* __restrict__ f2,
                                         int g, int mt, int wave, int lane, fv16 acc[4]) {
    int half = lane >> 5, r = lane & 31;
    const bf* Ap = f1 + ((size_t)g * NPG + mt * 32 + r) * F3 + half * 8;
    sv8 a0 = *(const sv8*)(Ap +  0);
    sv8 a1 = *(const sv8*)(Ap + 16);
    sv8 a2 = *(const sv8*)(Ap + 32);
    sv8 a3 = *(const sv8*)(Ap + 48);
#pragma unroll
    for (int j = 0; j < 4; j++) {
        int nt = j * 4 + wave;
        const bf* Bp = f2 + ((size_t)g * NPG + nt * 32 + r) * F3 + half * 8;
#pragma unroll
        for (int i = 0; i < 16; i++) acc[j][i] = 0.f;
        acc[j] = __builtin_amdgcn_mfma_f32_32x32x16_bf16(a0, *(const sv8*)(Bp +  0), acc[j], 0, 0, 0);
        acc[j] = __builtin_amdgcn_mfma_f32_32x32x16_bf16(a1, *(const sv8*)(Bp + 16), acc[j], 0, 0, 0);
        acc[j] = __builtin_amdgcn_mfma_f32_32x32x16_bf16(a2, *(const sv8*)(Bp + 32), acc[j], 0, 0, 0);
        acc[j] = __builtin_amdgcn_mfma_f32_32x32x16_bf16(a3, *(const sv8*)(Bp + 48), acc[j], 0, 0, 0);
    }
}

// ---------------- combo: simm (blocks 0..2047) + meanp (blocks 2048..4095) ----------------
__global__ __launch_bounds__(256) void simmean_k(const bf* __restrict__ f1, const bf* __restrict__ f2,
                                                 float* __restrict__ statmin, float* __restrict__ statmax,
                                                 float* __restrict__ meanp) {
    __shared__ float red[256];
    int bid = blockIdx.x;
    int t = threadIdx.x, wave = t >> 6, lane = t & 63;
    if (bid < 2048) {
        int g = bid >> 4, mt = bid & 15;
        fv16 acc[4];
        sim_tile(f1, f2, g, mt, wave, lane, acc);
        float mn = 1e30f, mx = -1e30f;
#pragma unroll
        for (int j = 0; j < 4; j++)
#pragma unroll
            for (int i = 0; i < 16; i++) {
                mn = fminf(mn, acc[j][i]);
                mx = fmaxf(mx, acc[j][i]);
            }
        for (int o = 32; o; o >>= 1) {
            mn = fminf(mn, __shfl_down(mn, o));
            mx = fmaxf(mx, __shfl_down(mx, o));
        }
        if (lane == 0) { red[wave] = mn; red[4 + wave] = mx; }
        __syncthreads();
        if (t == 0) {
            statmin[g * 16 + mt] = fminf(fminf(red[0], red[1]), fminf(red[2], red[3]));
            statmax[g * 16 + mt] = fmaxf(fmaxf(red[4], red[5]), fmaxf(red[6], red[7]));
        }
    } else {
        int idx = bid - 2048;
        int side = idx >> 10, rem = idx & 1023;
        int ch = rem >> 7, g = rem & 127;
        const bf* xp = (side ? f2 : f1) + ((size_t)g * NPG + ch * 64) * F3;
        int f = t & 63;
        float m = 0.f;
#pragma unroll 4
        for (int i = 0; i < 16; i++) m += b2f(xp[(size_t)(wave * 16 + i) * F3 + f]);
        red[t] = m;
        __syncthreads();
        if (t < 64) meanp[(((size_t)side * BGR + g) * 8 + ch) * 64 + t] =
            red[t] + red[64 + t] + red[128 + t] + red[192 + t];
    }
}

// ---------------- combo: simh (blocks 0..2047) + ctx (blocks 2048..2303) ----------------
__global__ __launch_bounds__(256) void simhctx_k(const bf* __restrict__ f1, const bf* __restrict__ f2,
                                                 const float* __restrict__ statmin, const float* __restrict__ statmax,
                                                 int* __restrict__ hist_p,
                                                 const float* __restrict__ meanp, const float* __restrict__ Watt,
                                                 float* __restrict__ ctxb) {
    __shared__ int ph[256 * 17];
    __shared__ int pr[256];
    int bid = blockIdx.x;
    int t = threadIdx.x, wave = t >> 6, lane = t & 63;
    if (bid < 2048) {
        int g = bid >> 4, mt = bid & 15;
#pragma unroll
        for (int b = 0; b < BINS; b++) ph[t * 17 + b] = 0;
        float pm = (lane < 16) ? statmin[g * 16 + lane] : 1e30f;
        float px = (lane < 16) ? statmax[g * 16 + lane] : -1e30f;
        for (int o = 8; o; o >>= 1) {
            pm = fminf(pm, __shfl_down(pm, o));
            px = fmaxf(px, __shfl_down(px, o));
        }
        float vmin = sigm(__shfl(pm, 0));
        float vmax = sigm(__shfl(px, 0));
        float width = (vmax - vmin) / (float)BINS;
        float inv = 1.0f / (width > 0.f ? width : 1.0f);
        fv16 acc[4];
        sim_tile(f1, f2, g, mt, wave, lane, acc);
#pragma unroll
        for (int j = 0; j < 4; j++)
#pragma unroll
            for (int i = 0; i < 16; i++) {
                float v = sigm(acc[j][i]);
                int bi = (int)floorf((v - vmin) * inv);
                bi = bi < 0 ? 0 : (bi > BINS - 1 ? BINS - 1 : bi);
                ph[t * 17 + bi] += 1;
            }
        __syncthreads();
        {
            int grp = t >> 4, bin = t & 15;
            int s = 0;
#pragma unroll
            for (int j = 0; j < 16; j++) s += ph[(grp * 16 + j) * 17 + bin];
            pr[t] = s;
        }
        __syncthreads();
        if (t < BINS) {
            int tot = 0;
#pragma unroll
            for (int j = 0; j < 16; j++) tot += pr[j * 16 + t];
            hist_p[((size_t)g * 16 + mt) * BINS + t] = tot;
        }
    } else {
        int idx = bid - 2048;
        int side = idx >> 7, g = idx & 127;
        float* sm = (float*)pr;
        if (t < 64) {
            float m = 0.f;
#pragma unroll
            for (int ch = 0; ch < 8; ch++) m += meanp[(((size_t)side * BGR + g) * 8 + ch) * 64 + t];
            sm[t] = m * (1.0f / (float)NPG);
        }
        __syncthreads();
        if (t < 64) {
            float acc = 0.f;
#pragma unroll 8
            for (int i = 0; i < F3; i++) acc += sm[i] * Watt[i * F3 + t];
            ctxb[((size_t)side * BGR + g) * F3 + t] = tanhf(acc);
        }
    }
}

// coef + weighted partial pool; grid (BGR, 8, 2)
__global__ __launch_bounds__(256) void cpool_k(const bf* __restrict__ f1, const bf* __restrict__ f2,
                                               const float* __restrict__ ctxb, float* __restrict__ poolp) {
    int g = blockIdx.x, ch = blockIdx.y, side = blockIdx.z;
    const bf* xp = (side ? f2 : f1) + ((size_t)g * NPG + ch * 64) * F3;
    int t = threadIdx.x, w = t >> 6, f = t & 63;
    float cx = ctxb[((size_t)side * BGR + g) * F3 + f];
    float acc = 0.f;
    for (int i = 0; i < 16; i++) {
        float v = b2f(xp[(size_t)(w * 16 + i) * F3 + f]);
        float d = v * cx;
#pragma unroll
        for (int o = 1; o < 64; o <<= 1) d += __shfl_xor(d, o);
        acc += sigm(d) * v;
    }
    __shared__ float red[256];
    red[t] = acc;
    __syncthreads();
    if (t < 64) poolp[(((size_t)side * BGR + g) * 8 + ch) * 64 + t] =
        red[t] + red[64 + t] + red[128 + t] + red[192 + t];
}

// ---------------- tensor network + tail MLP ----------------
__global__ __launch_bounds__(256) void final_k(const float* __restrict__ poolp,
                                               const float* __restrict__ Wt, const float* __restrict__ Wtb,
                                               const float* __restrict__ tb, const int* __restrict__ hist_p,
                                               const float* __restrict__ W1, const float* __restrict__ b1,
                                               const float* __restrict__ Ws, const float* __restrict__ bs,
                                               float* __restrict__ out) {
    int b = blockIdx.x, t = threadIdx.x;
    __shared__ float cat[128];
    __shared__ float sacc[256];
    __shared__ float feat[32];
    __shared__ float hb[32];
    if (t < 128) {
        int side = t >> 6, f = t & 63;
        float s = 0.f;
#pragma unroll
        for (int ch = 0; ch < 8; ch++) s += poolp[(((size_t)side * BGR + b) * 8 + ch) * 64 + f];
        cat[t] = s;
    }
    __syncthreads();
    int k = t & 15, c = t >> 4;
    float acc = 0.f;
    for (int q = 0; q < 256; q++) {
        int ij = c * 256 + q;
        int i = ij >> 6, j = ij & 63;
        acc += cat[i] * cat[64 + j] * Wt[ij * KT + k];
    }
    sacc[t] = acc;
    __syncthreads();
    if (t < KT) {
        float sc = 0.f;
        for (int c2 = 0; c2 < 16; c2++) sc += sacc[c2 * 16 + t];
        float bt = 0.f;
        for (int i = 0; i < 128; i++) bt += cat[i] * Wtb[t * 128 + i];
        float tv = sc + bt + tb[t];
        feat[t] = tv > 0.f ? tv : 0.f;
        int hsum = 0;
#pragma unroll
        for (int j = 0; j < 16; j++) hsum += hist_p[((size_t)b * 16 + j) * BINS + t];
        feat[KT + t] = (float)hsum * (1.0f / (float)(NPG * NPG));
    }
    __syncthreads();
    if (t < BN) {
        float a = 0.f;
        for (int i = 0; i < KT + BINS; i++) a += feat[i] * W1[i * BN + t];
        a += b1[t];
        hb[t] = a > 0.f ? a : 0.f;
    }
    __syncthreads();
    if (t == 0) {
        float s = bs[0];
        for (int j = 0; j < BN; j++) s += hb[j] * Ws[j];
        out[b] = sigm(s);
    }
}

// ---------------- launch ----------------
extern "C" void kernel_launch(void* const* d_in, const int* in_sizes, int n_in,
                              void* d_out, int out_size, void* d_ws, size_t ws_size,
                              hipStream_t stream) {
    const float* x1   = (const float*)d_in[0];
    const float* x2   = (const float*)d_in[1];
    const int*   ei1  = (const int*)d_in[2];
    const int*   ei2  = (const int*)d_in[3];
    const float* Wc1  = (const float*)d_in[6];
    const float* bc1  = (const float*)d_in[7];
    const float* Wc2  = (const float*)d_in[8];
    const float* bc2  = (const float*)d_in[9];
    const float* Wc3  = (const float*)d_in[10];
    const float* bc3  = (const float*)d_in[11];
    const float* Watt = (const float*)d_in[12];
    const float* Wt   = (const float*)d_in[13];
    const float* Wtb  = (const float*)d_in[14];
    const float* tb   = (const float*)d_in[15];
    const float* W1   = (const float*)d_in[16];
    const float* b1   = (const float*)d_in[17];
    const float* Ws   = (const float*)d_in[18];
    const float* bs   = (const float*)d_in[19];
    float* out = (float*)d_out;

    // ---- workspace layout (~80 MB) ----
    char* wsb = (char*)d_ws;
    size_t o = 0;
    auto alloc = [&](size_t bytes) -> void* {
        void* p = wsb + o;
        o = (o + bytes + 255) & ~(size_t)255;
        return p;
    };
    bf* f1b  = (bf*)alloc((size_t)NTOT * F3 * 2);     //  8 MB
    bf* f2b  = (bf*)alloc((size_t)NTOT * F3 * 2);     //  8 MB
    bf* X    = (bf*)alloc((size_t)2 * NTOT * F2 * 2); // 24 MB (h2, both sides)
    bf* Y    = (bf*)alloc((size_t)2 * NTOT * F2 * 2); // 24 MB (t2/t3, both sides)
    int* off   = (int*)alloc((size_t)2 * (NTOT + 1) * 4);
    unsigned* ecsr = (unsigned*)alloc((size_t)2 * NEDGE * 4);        // 4 MB packed src|norm
    unsigned* bucket = (unsigned*)alloc((size_t)2 * 128 * GCAP * 4); // 6.3 MB
    int* gcount = (int*)alloc(256 * 4);
    float* dinv = (float*)alloc((size_t)2 * NTOT * 4);
    float* statmin = (float*)alloc((size_t)BGR * 16 * 4);
    float* statmax = (float*)alloc((size_t)BGR * 16 * 4);
    int* hist_p = (int*)alloc((size_t)BGR * 16 * BINS * 4);
    float* meanp = (float*)alloc((size_t)2 * BGR * 8 * 64 * 4);
    float* ctx   = (float*)alloc((size_t)2 * BGR * F3 * 4);
    float* poolp = (float*)alloc((size_t)2 * BGR * 8 * 64 * 4);
    bf* wt1 = (bf*)alloc((size_t)NL * F1 * 2);   // Wt1[F1][NL]
    bf* wt2 = (bf*)alloc((size_t)F1 * F2 * 2);   // Wt2[F2][F1]
    bf* wt3 = (bf*)alloc((size_t)F2 * F3 * 2);   // Wt3[F3][F2]
    (void)ws_size; (void)in_sizes; (void)n_in; (void)out_size;

    // init: zero gcount + weight transpose (single dispatch)
    init_k<<<(NL * F1 + F1 * F2 + F2 * F3 + 255) / 256, 256, 0, stream>>>(Wc1, Wc2, Wc3, wt1, wt2, wt3, gcount);

    // ---- CSR build: bucket by graph, then per-graph sort (scan folded into csr_k) ----
    bucket_k<<<dim3(NEDGE / 1024, 2), 256, 0, stream>>>(ei1, ei2, gcount, bucket);
    csr_k<<<dim3(BGR, 2), 256, 0, stream>>>(bucket, gcount, off, dinv, ecsr);

    // ---- GCN stack ----
    // t2 = relu((A_hat x) W1 + b1) W2 -> Y   [fused layers 1+2, LDS C->A transform]
    aggemm12_k<<<dim3(NTOT / 128, 2), 256, 0, stream>>>(x1, x2, off, ecsr, dinv, wt1, bc1, wt2, Y);
    // h2 = relu(A_hat t2 + bc2) -> X
    agg_k<F2, 1><<<dim3((NTOT * (F2 / 4)) / 256, 2), 256, 0, stream>>>(Y, bc2, off, ecsr, dinv, X);
    // t3 = h2 Wc3 -> Y
    gemmm_k<F2, F3, 0, 0><<<dim3(NTOT / 128, 2), 256, 0, stream>>>(X, wt3, nullptr, Y);
    // f = A_hat t3 + bc3 -> f1b/f2b
    aggf_k<F3><<<dim3((NTOT * (F3 / 4)) / 256, 2), 256, 0, stream>>>(Y, bc3, off, ecsr, dinv, f1b, f2b);

    // ---- sim minmax + mean partials (one dispatch) ----
    simmean_k<<<4096, 256, 0, stream>>>(f1b, f2b, statmin, statmax, meanp);
    // ---- sim hist + ctx (one dispatch) ----
    simhctx_k<<<2048 + 256, 256, 0, stream>>>(f1b, f2b, statmin, statmax, hist_p, meanp, Watt, ctx);
    // ---- coef + weighted pool partials ----
    cpool_k<<<dim3(BGR, 8, 2), 256, 0, stream>>>(f1b, f2b, ctx, poolp);

    // ---- tensor network + MLP tail ----
    final_k<<<BGR, 256, 0, stream>>>(poolp, Wt, Wtb, tb, hist_p, W1, b1, Ws, bs, out);
}

// Round 13
// 320.889 us; speedup vs baseline: 1.1490x; 1.0587x over previous
//
#include <hip/hip_runtime.h>
#include <math.h>

#define NTOT  65536
#define NEDGE 524288
#define BGR   128
#define NPG   512
#define NL    32
#define F1    128
#define F2    96
#define F3    64
#define KT    16
#define BINS  16
#define BN    32
#define GCAP  6144   // per-graph edge bucket capacity (mean 4096, +32 sigma)

typedef unsigned short bf;
typedef __attribute__((ext_vector_type(8))) short sv8;    // 8 bf16 fragment (4 VGPRs)
typedef __attribute__((ext_vector_type(16))) float fv16;  // 32x32 mfma accumulator

// ---------------- helpers ----------------
__device__ __forceinline__ float b2f(bf v) { return __uint_as_float(((unsigned)v) << 16); }
__device__ __forceinline__ bf f2b(float f) {
    unsigned u = __float_as_uint(f);
    return (bf)((u + 0x7FFF + ((u >> 16) & 1)) >> 16);  // RNE
}
__device__ __forceinline__ float sigm(float x) { return 1.f / (1.f + expf(-x)); }
// XCD swizzle: bid = 8*((g>>3)*NBLK + i) + (g&7)  ->  all blocks of graph g share bid%8
__device__ __forceinline__ void unswizzle(int bid, int nblk, int& g, int& i) {
    int q = bid >> 3;
    g = ((q / nblk) << 3) | (bid & 7);
    i = q % nblk;
}

// ---------------- init: zero gcount + transpose/convert all weights ----------------
__global__ __launch_bounds__(256) void init_k(const float* __restrict__ W1, const float* __restrict__ W2,
                                              const float* __restrict__ W3,
                                              bf* __restrict__ T1, bf* __restrict__ T2, bf* __restrict__ T3,
                                              int* __restrict__ gcount) {
    int i = blockIdx.x * 256 + threadIdx.x;
    if (i < 256) gcount[i] = 0;
    if (i < NL * F1) {
        int co = i >> 5, ci = i & 31;
        T1[i] = f2b(W1[ci * F1 + co]);
    } else if (i < NL * F1 + F1 * F2) {
        int i2 = i - NL * F1;
        int co = i2 >> 7, ci = i2 & 127;
        T2[i2] = f2b(W2[ci * F2 + co]);
    } else if (i < NL * F1 + F1 * F2 + F2 * F3) {
        int i3 = i - NL * F1 - F1 * F2;
        int co = i3 / 96, ci = i3 - co * 96;
        T3[i3] = f2b(W3[ci * F3 + co]);
    }
}

// ---------------- CSR build: graph-bucket then per-graph sort ----------------
__global__ __launch_bounds__(256) void bucket_k(const int* __restrict__ ei1, const int* __restrict__ ei2,
                                                int* __restrict__ gcount, unsigned* __restrict__ bucket) {
    int side = blockIdx.y;
    const int* src = side ? ei2 : ei1;
    const int* dst = src + NEDGE;
    __shared__ int bc[128], bbase[128], bcur[128];
    int t = threadIdx.x;
    if (t < 128) { bc[t] = 0; bcur[t] = 0; }
    __syncthreads();
    int e0 = blockIdx.x * 1024;
    unsigned lp[4];
    int lg[4];
#pragma unroll
    for (int i = 0; i < 4; i++) {
        int e = e0 + i * 256 + t;
        int s = src[e], d = dst[e];
        int g = d >> 9;
        lp[i] = ((unsigned)s << 9) | (unsigned)(d & 511);
        lg[i] = g;
        atomicAdd(&bc[g], 1);
    }
    __syncthreads();
    if (t < 128 && bc[t] > 0) bbase[t] = atomicAdd(&gcount[side * 128 + t], bc[t]);
    __syncthreads();
#pragma unroll
    for (int i = 0; i < 4; i++) {
        int g = lg[i];
        int pos = bbase[g] + atomicAdd(&bcur[g], 1);
        if (pos < GCAP) bucket[((size_t)side * 128 + g) * GCAP + pos] = lp[i];
    }
}

// Phase B: one block per graph; CSR built in LDS; in-block scan of per-graph counts.
// Edge record 4B: src(u16)|norm(bf16)<<16.
__global__ __launch_bounds__(256) void csr_k(const unsigned* __restrict__ bucket, const int* __restrict__ gcount,
                                             int* __restrict__ off, float* __restrict__ dinv,
                                             unsigned* __restrict__ ecsr) {
    int side = blockIdx.y, g = blockIdx.x, t = threadIdx.x;
    __shared__ int ncnt[512];
    __shared__ int c2[256];
    __shared__ int cur[512];
    __shared__ float dloc[512];
    __shared__ int gs[128];
    ncnt[t] = 0; ncnt[t + 256] = 0;
    if (t < 128) gs[t] = gcount[side * 128 + t];
    __syncthreads();
    for (int o = 1; o < 128; o <<= 1) {
        int v = (t >= o && t < 128) ? gs[t - o] : 0;
        __syncthreads();
        if (t < 128) gs[t] += v;
        __syncthreads();
    }
    int cnt = gcount[side * 128 + g];
    cnt = cnt < GCAP ? cnt : GCAP;
    int base = side * NEDGE + (g > 0 ? gs[g - 1] : 0);
    const unsigned* bk = bucket + ((size_t)side * 128 + g) * GCAP;
    for (int i = t; i < cnt; i += 256) atomicAdd(&ncnt[bk[i] & 511], 1);
    __syncthreads();
    int e0 = ncnt[2 * t], e1 = ncnt[2 * t + 1];
    c2[t] = e0 + e1;
    __syncthreads();
    for (int o = 1; o < 256; o <<= 1) {
        int v = (t >= o) ? c2[t - o] : 0;
        __syncthreads();
        c2[t] += v;
        __syncthreads();
    }
    int ex = c2[t] - (e0 + e1);
    cur[2 * t] = ex;
    cur[2 * t + 1] = ex + e0;
    float d0 = rsqrtf((float)e0 + 1.f), d1 = rsqrtf((float)e1 + 1.f);
    dloc[2 * t] = d0; dloc[2 * t + 1] = d1;
    int node0 = g * NPG + 2 * t;
    int* offs = off + side * (NTOT + 1);
    offs[node0] = base + ex;
    offs[node0 + 1] = base + ex + e0;
    *(float2*)(dinv + (size_t)side * NTOT + node0) = make_float2(d0, d1);
    if (g == BGR - 1 && t == 0) offs[NTOT] = (side + 1) * NEDGE;
    __syncthreads();
    for (int i = t; i < cnt; i += 256) {
        unsigned p = bk[i];
        int dl = p & 511;
        int s = p >> 9;
        int pos = atomicAdd(&cur[dl], 1);
        float nm = dloc[s & 511] * dloc[dl];
        ecsr[base + pos] = (unsigned)s | ((unsigned)f2b(nm) << 16);
    }
}

// ---------------- fused layers 1+2: t2 = relu((A_hat x) W1 + b1) W2 ----------------
// XCD-swizzled (4 blocks/graph); wave-private LDS tile for the C->A transform.
#define HSTR 136   // 128 + 8 bf16 pad
__global__ __launch_bounds__(256) void aggemm12_k(const float* __restrict__ x1, const float* __restrict__ x2,
                                                  const int* __restrict__ off, const unsigned* __restrict__ ecsr,
                                                  const float* __restrict__ dinv,
                                                  const bf* __restrict__ wt1, const float* __restrict__ bc1,
                                                  const bf* __restrict__ wt2, bf* __restrict__ Yb) {
    __shared__ bf Hs[128 * HSTR];   // 34816 B
    int side = blockIdx.y;
    const float* x = side ? x2 : x1;
    const int* offs = off + side * (NTOT + 1);
    const float* dv = dinv + (size_t)side * NTOT;
    bf* Y = Yb + (size_t)side * NTOT * F2;
    int g, ib;
    unswizzle(blockIdx.x, 4, g, ib);
    int wave = threadIdx.x >> 6, lane = threadIdx.x & 63;
    int half = lane >> 5, r = lane & 31;
    int row0 = g * NPG + ib * 128 + wave * 32;
    int n = row0 + r;
    float z[16];
    float d = dv[n];
    float sc = d * d;
    const float* xr = x + (size_t)n * NL + half * 8;
#pragma unroll
    for (int ks = 0; ks < 2; ks++) {
        float4 v0 = *(const float4*)(xr + ks * 16);
        float4 v1 = *(const float4*)(xr + ks * 16 + 4);
        z[ks * 8 + 0] = v0.x * sc; z[ks * 8 + 1] = v0.y * sc;
        z[ks * 8 + 2] = v0.z * sc; z[ks * 8 + 3] = v0.w * sc;
        z[ks * 8 + 4] = v1.x * sc; z[ks * 8 + 5] = v1.y * sc;
        z[ks * 8 + 6] = v1.z * sc; z[ks * 8 + 7] = v1.w * sc;
    }
    int e0 = offs[n], e1 = offs[n + 1];
    for (int j = e0; j < e1; j++) {
        unsigned en = ecsr[j];
        int s = en & 0xFFFF;
        float w = b2f((bf)(en >> 16));
        const float* xs = x + (size_t)s * NL + half * 8;
#pragma unroll
        for (int ks = 0; ks < 2; ks++) {
            float4 u0 = *(const float4*)(xs + ks * 16);
            float4 u1 = *(const float4*)(xs + ks * 16 + 4);
            z[ks * 8 + 0] += w * u0.x; z[ks * 8 + 1] += w * u0.y;
            z[ks * 8 + 2] += w * u0.z; z[ks * 8 + 3] += w * u0.w;
            z[ks * 8 + 4] += w * u1.x; z[ks * 8 + 5] += w * u1.y;
            z[ks * 8 + 6] += w * u1.z; z[ks * 8 + 7] += w * u1.w;
        }
    }
    sv8 a0, a1;
#pragma unroll
    for (int jj = 0; jj < 8; jj++) {
        a0[jj] = (short)f2b(z[jj]);
        a1[jj] = (short)f2b(z[8 + jj]);
    }
#pragma unroll
    for (int nt = 0; nt < F1 / 32; nt++) {
        const bf* Bp = wt1 + (size_t)(nt * 32 + r) * NL + half * 8;
        sv8 b0 = *(const sv8*)(Bp);
        sv8 b1 = *(const sv8*)(Bp + 16);
        fv16 acc;
#pragma unroll
        for (int i = 0; i < 16; i++) acc[i] = 0.f;
        acc = __builtin_amdgcn_mfma_f32_32x32x16_bf16(a0, b0, acc, 0, 0, 0);
        acc = __builtin_amdgcn_mfma_f32_32x32x16_bf16(a1, b1, acc, 0, 0, 0);
        float bv = bc1[nt * 32 + r];
#pragma unroll
        for (int i = 0; i < 16; i++) {
            int rr = (i & 3) + 8 * (i >> 2) + 4 * half;
            Hs[(wave * 32 + rr) * HSTR + nt * 32 + r] = f2b(fmaxf(acc[i] + bv, 0.f));
        }
    }
    // wave-private rows: no barrier needed
    sv8 a[8];
#pragma unroll
    for (int k = 0; k < 8; k++)
        a[k] = *(const sv8*)&Hs[(wave * 32 + r) * HSTR + k * 16 + half * 8];
#pragma unroll
    for (int nt = 0; nt < F2 / 32; nt++) {
        const bf* Bp = wt2 + (size_t)(nt * 32 + r) * F1 + half * 8;
        fv16 acc;
#pragma unroll
        for (int i = 0; i < 16; i++) acc[i] = 0.f;
#pragma unroll
        for (int k = 0; k < 8; k++)
            acc = __builtin_amdgcn_mfma_f32_32x32x16_bf16(a[k], *(const sv8*)(Bp + k * 16), acc, 0, 0, 0);
#pragma unroll
        for (int i = 0; i < 16; i++) {
            int rr = (i & 3) + 8 * (i >> 2) + 4 * half;
            Y[(size_t)(row0 + rr) * F2 + nt * 32 + r] = f2b(acc[i]);
        }
    }
}

// ---------------- MFMA GEMM (both sides via blockIdx.y) ----------------
template <int CIN, int COUT, int BIAS, int RELU>
__global__ __launch_bounds__(256) void gemmm_k(const bf* __restrict__ Xb, const bf* __restrict__ Wt,
                                               const float* __restrict__ bias, bf* __restrict__ outb) {
    int side = blockIdx.y;
    const bf* X = Xb + (size_t)side * NTOT * CIN;
    bf* out = outb + (size_t)side * NTOT * COUT;
    int wave = threadIdx.x >> 6, lane = threadIdx.x & 63;
    int half = lane >> 5, r = lane & 31;
    int row0 = blockIdx.x * 128 + wave * 32;
    const bf* Ap = X + (size_t)(row0 + r) * CIN + half * 8;
    sv8 a[CIN / 16];
#pragma unroll
    for (int k = 0; k < CIN / 16; k++) a[k] = *(const sv8*)(Ap + k * 16);
#pragma unroll
    for (int nt = 0; nt < COUT / 32; nt++) {
        const bf* Bp = Wt + (size_t)(nt * 32 + r) * CIN + half * 8;
        fv16 acc;
#pragma unroll
        for (int i = 0; i < 16; i++) acc[i] = 0.f;
#pragma unroll
        for (int k = 0; k < CIN / 16; k++)
            acc = __builtin_amdgcn_mfma_f32_32x32x16_bf16(a[k], *(const sv8*)(Bp + k * 16), acc, 0, 0, 0);
        float bv = BIAS ? bias[nt * 32 + r] : 0.f;
#pragma unroll
        for (int i = 0; i < 16; i++) {
            int rr = (i & 3) + 8 * (i >> 2) + 4 * half;
            float v = acc[i] + bv;
            if (RELU) v = fmaxf(v, 0.f);
            out[(size_t)(row0 + rr) * COUT + nt * 32 + r] = f2b(v);
        }
    }
}

// ---------------- GCN aggregation (XCD-swizzled, 2x edge unroll) ----------------
template <int C, int RELU>
__global__ __launch_bounds__(256) void agg_k(const bf* __restrict__ hinb, const float* __restrict__ bias,
                                             const int* __restrict__ off, const unsigned* __restrict__ ecsr,
                                             const float* __restrict__ dinv, bf* __restrict__ outb) {
    constexpr int C4 = C / 4;
    constexpr int NBLK = NPG * C4 / 256;   // blocks per graph (48 for F2, 32 for F3)
    int side = blockIdx.y;
    const bf* hin = hinb + (size_t)side * NTOT * C;
    bf* out = outb + (size_t)side * NTOT * C;
    const int* offs = off + side * (NTOT + 1);
    int g, ib;
    unswizzle(blockIdx.x, NBLK, g, ib);
    int item = ib * 256 + threadIdx.x;
    int node = g * NPG + item / C4;
    int c = (item % C4) * 4;
    float d = dinv[(size_t)side * NTOT + node];
    float sc = d * d;
    ushort4 h = *(const ushort4*)(hin + (size_t)node * C + c);
    float ax = b2f(h.x) * sc, ay = b2f(h.y) * sc, az = b2f(h.z) * sc, aw = b2f(h.w) * sc;
    int e0 = offs[node], e1 = offs[node + 1];
    int j = e0;
    for (; j + 2 <= e1; j += 2) {
        unsigned ena = ecsr[j], enb = ecsr[j + 1];
        int sa = ena & 0xFFFF, sb = enb & 0xFFFF;
        float wa = b2f((bf)(ena >> 16)), wb = b2f((bf)(enb >> 16));
        ushort4 ha = *(const ushort4*)(hin + (size_t)sa * C + c);
        ushort4 hb = *(const ushort4*)(hin + (size_t)sb * C + c);
        ax += wa * b2f(ha.x) + wb * b2f(hb.x);
        ay += wa * b2f(ha.y) + wb * b2f(hb.y);
        az += wa * b2f(ha.z) + wb * b2f(hb.z);
        aw += wa * b2f(ha.w) + wb * b2f(hb.w);
    }
    if (j < e1) {
        unsigned en = ecsr[j];
        int s = en & 0xFFFF;
        float w = b2f((bf)(en >> 16));
        ushort4 hs = *(const ushort4*)(hin + (size_t)s * C + c);
        ax += w * b2f(hs.x); ay += w * b2f(hs.y); az += w * b2f(hs.z); aw += w * b2f(hs.w);
    }
    float4 bv = *(const float4*)(bias + c);
    ax += bv.x; ay += bv.y; az += bv.z; aw += bv.w;
    if (RELU) {
        ax = fmaxf(ax, 0.f); ay = fmaxf(ay, 0.f); az = fmaxf(az, 0.f); aw = fmaxf(aw, 0.f);
    }
    ushort4 o;
    o.x = f2b(ax); o.y = f2b(ay); o.z = f2b(az); o.w = f2b(aw);
    *(ushort4*)(out + (size_t)node * C + c) = o;
}

// final agg writes to separate f buffers (XCD-swizzled)
template <int C>
__global__ __launch_bounds__(256) void aggf_k(const bf* __restrict__ hinb, const float* __restrict__ bias,
                                              const int* __restrict__ off, const unsigned* __restrict__ ecsr,
                                              const float* __restrict__ dinv,
                                              bf* __restrict__ f1, bf* __restrict__ f2) {
    constexpr int C4 = C / 4;
    constexpr int NBLK = NPG * C4 / 256;
    int side = blockIdx.y;
    const bf* hin = hinb + (size_t)side * NTOT * C;
    bf* out = side ? f2 : f1;
    const int* offs = off + side * (NTOT + 1);
    int g, ib;
    unswizzle(blockIdx.x, NBLK, g, ib);
    int item = ib * 256 + threadIdx.x;
    int node = g * NPG + item / C4;
    int c = (item % C4) * 4;
    float d = dinv[(size_t)side * NTOT + node];
    float sc = d * d;
    ushort4 h = *(const ushort4*)(hin + (size_t)node * C + c);
    float ax = b2f(h.x) * sc, ay = b2f(h.y) * sc, az = b2f(h.z) * sc, aw = b2f(h.w) * sc;
    int e0 = offs[node], e1 = offs[node + 1];
    int j = e0;
    for (; j + 2 <= e1; j += 2) {
        unsigned ena = ecsr[j], enb = ecsr[j + 1];
        int sa = ena & 0xFFFF, sb = enb & 0xFFFF;
        float wa = b2f((bf)(ena >> 16)), wb = b2f((bf)(enb >> 16));
        ushort4 ha = *(const ushort4*)(hin + (size_t)sa * C + c);
        ushort4 hb = *(const ushort4*)(hin + (size_t)sb * C + c);
        ax += wa * b2f(ha.x) + wb * b2f(hb.x);
        ay += wa * b2f(ha.y) + wb * b2f(hb.y);
        az += wa * b2f(ha.z) + wb * b2f(hb.z);
        aw += wa * b2f(ha.w) + wb * b2f(hb.w);
    }
    if (j < e1) {
        unsigned en = ecsr[j];
        int s = en & 0xFFFF;
        float w = b2f((bf)(en >> 16));
        ushort4 hs = *(const ushort4*)(hin + (size_t)s * C + c);
        ax += w * b2f(hs.x); ay += w * b2f(hs.y); az += w * b2f(hs.z); aw += w * b2f(hs.w);
    }
    float4 bv = *(const float4*)(bias + c);
    ax += bv.x; ay += bv.y; az += bv.z; aw += bv.w;
    ushort4 o;
    o.x = f2b(ax); o.y = f2b(ay); o.z = f2b(az); o.w = f2b(aw);
    *(ushort4*)(out + (size_t)node * C + c) = o;
}

// ---------------- sim tile core ----------------
__device__ __forceinline__ void sim_tile(const bf* __restrict__ f1, const bf* __restrict__ f2,
                                         int g, int mt, int wave, int lane, fv16 acc[4]) {
    int half = lane >> 5, r = lane & 31;
    const bf* Ap = f1 + ((size_t)g * NPG + mt * 32 + r) * F3 + half * 8;
    sv8 a0 = *(const sv8*)(Ap +  0);
    sv8 a1 = *(const sv8*)(Ap + 16);
    sv8 a2 = *(const sv8*)(Ap + 32);
    sv8 a3 = *(const sv8*)(Ap + 48);
#pragma unroll
    for (int j = 0; j < 4; j++) {
        int nt = j * 4 + wave;
        const bf* Bp = f2 + ((size_t)g * NPG + nt * 32 + r) * F3 + half * 8;
#pragma unroll
        for (int i = 0; i < 16; i++) acc[j][i] = 0.f;
        acc[j] = __builtin_amdgcn_mfma_f32_32x32x16_bf16(a0, *(const sv8*)(Bp +  0), acc[j], 0, 0, 0);
        acc[j] = __builtin_amdgcn_mfma_f32_32x32x16_bf16(a1, *(const sv8*)(Bp + 16), acc[j], 0, 0, 0);
        acc[j] = __builtin_amdgcn_mfma_f32_32x32x16_bf16(a2, *(const sv8*)(Bp + 32), acc[j], 0, 0, 0);
        acc[j] = __builtin_amdgcn_mfma_f32_32x32x16_bf16(a3, *(const sv8*)(Bp + 48), acc[j], 0, 0, 0);
    }
}

// ---------------- combo: simm (blocks 0..2047, swizzled) + meanp (2048..4095) ----------------
__global__ __launch_bounds__(256) void simmean_k(const bf* __restrict__ f1, const bf* __restrict__ f2,
                                                 float* __restrict__ statmin, float* __restrict__ statmax,
                                                 float* __restrict__ meanp) {
    __shared__ float red[256];
    int bid = blockIdx.x;
    int t = threadIdx.x, wave = t >> 6, lane = t & 63;
    if (bid < 2048) {
        int g, mt;
        unswizzle(bid, 16, g, mt);
        fv16 acc[4];
        sim_tile(f1, f2, g, mt, wave, lane, acc);
        float mn = 1e30f, mx = -1e30f;
#pragma unroll
        for (int j = 0; j < 4; j++)
#pragma unroll
            for (int i = 0; i < 16; i++) {
                mn = fminf(mn, acc[j][i]);
                mx = fmaxf(mx, acc[j][i]);
            }
        for (int o = 32; o; o >>= 1) {
            mn = fminf(mn, __shfl_down(mn, o));
            mx = fmaxf(mx, __shfl_down(mx, o));
        }
        if (lane == 0) { red[wave] = mn; red[4 + wave] = mx; }
        __syncthreads();
        if (t == 0) {
            statmin[g * 16 + mt] = fminf(fminf(red[0], red[1]), fminf(red[2], red[3]));
            statmax[g * 16 + mt] = fmaxf(fmaxf(red[4], red[5]), fmaxf(red[6], red[7]));
        }
    } else {
        int idx = bid - 2048;
        int side = idx >> 10, rem = idx & 1023;
        int ch = rem >> 7, g = rem & 127;
        const bf* xp = (side ? f2 : f1) + ((size_t)g * NPG + ch * 64) * F3;
        int f = t & 63;
        float m = 0.f;
#pragma unroll 4
        for (int i = 0; i < 16; i++) m += b2f(xp[(size_t)(wave * 16 + i) * F3 + f]);
        red[t] = m;
        __syncthreads();
        if (t < 64) meanp[(((size_t)side * BGR + g) * 8 + ch) * 64 + t] =
            red[t] + red[64 + t] + red[128 + t] + red[192 + t];
    }
}

// ---------------- combo: simh (blocks 0..2047, swizzled) + ctx (2048..2303) ----------------
__global__ __launch_bounds__(256) void simhctx_k(const bf* __restrict__ f1, const bf* __restrict__ f2,
                                                 const float* __restrict__ statmin, const float* __restrict__ statmax,
                                                 int* __restrict__ hist_p,
                                                 const float* __restrict__ meanp, const float* __restrict__ Watt,
                                                 float* __restrict__ ctxb) {
    __shared__ int ph[256 * 17];
    __shared__ int pr[256];
    int bid = blockIdx.x;
    int t = threadIdx.x, wave = t >> 6, lane = t & 63;
    if (bid < 2048) {
        int g, mt;
        unswizzle(bid, 16, g, mt);
#pragma unroll
        for (int b = 0; b < BINS; b++) ph[t * 17 + b] = 0;
        float pm = (lane < 16) ? statmin[g * 16 + lane] : 1e30f;
        float px = (lane < 16) ? statmax[g * 16 + lane] : -1e30f;
        for (int o = 8; o; o >>= 1) {
            pm = fminf(pm, __shfl_down(pm, o));
            px = fmaxf(px, __shfl_down(px, o));
        }
        float vmin = sigm(__shfl(pm, 0));
        float vmax = sigm(__shfl(px, 0));
        float width = (vmax - vmin) / (float)BINS;
        float inv = 1.0f / (width > 0.f ? width : 1.0f);
        fv16 acc[4];
        sim_tile(f1, f2, g, mt, wave, lane, acc);
#pragma unroll
        for (int j = 0; j < 4; j++)
#pragma unroll
            for (int i = 0; i < 16; i++) {
                float v = sigm(acc[j][i]);
                int bi = (int)floorf((v - vmin) * inv);
                bi = bi < 0 ? 0 : (bi > BINS - 1 ? BINS - 1 : bi);
                ph[t * 17 + bi] += 1;
            }
        __syncthreads();
        {
            int grp = t >> 4, bin = t & 15;
            int s = 0;
#pragma unroll
            for (int j = 0; j < 16; j++) s += ph[(grp * 16 + j) * 17 + bin];
            pr[t] = s;
        }
        __syncthreads();
        if (t < BINS) {
            int tot = 0;
#pragma unroll
            for (int j = 0; j < 16; j++) tot += pr[j * 16 + t];
            hist_p[((size_t)g * 16 + mt) * BINS + t] = tot;
        }
    } else {
        int idx = bid - 2048;
        int side = idx >> 7, g = idx & 127;
        float* sm = (float*)pr;
        if (t < 64) {
            float m = 0.f;
#pragma unroll
            for (int ch = 0; ch < 8; ch++) m += meanp[(((size_t)side * BGR + g) * 8 + ch) * 64 + t];
            sm[t] = m * (1.0f / (float)NPG);
        }
        __syncthreads();
        if (t < 64) {
            float acc = 0.f;
#pragma unroll 8
            for (int i = 0; i < F3; i++) acc += sm[i] * Watt[i * F3 + t];
            ctxb[((size_t)side * BGR + g) * F3 + t] = tanhf(acc);
        }
    }
}

// coef + weighted partial pool; grid (BGR, 8, 2)
__global__ __launch_bounds__(256) void cpool_k(const bf* __restrict__ f1, const bf* __restrict__ f2,
                                               const float* __restrict__ ctxb, float* __restrict__ poolp) {
    int g = blockIdx.x, ch = blockIdx.y, side = blockIdx.z;
    const bf* xp = (side ? f2 : f1) + ((size_t)g * NPG + ch * 64) * F3;
    int t = threadIdx.x, w = t >> 6, f = t & 63;
    float cx = ctxb[((size_t)side * BGR + g) * F3 + f];
    float acc = 0.f;
    for (int i = 0; i < 16; i++) {
        float v = b2f(xp[(size_t)(w * 16 + i) * F3 + f]);
        float d = v * cx;
#pragma unroll
        for (int o = 1; o < 64; o <<= 1) d += __shfl_xor(d, o);
        acc += sigm(d) * v;
    }
    __shared__ float red[256];
    red[t] = acc;
    __syncthreads();
    if (t < 64) poolp[(((size_t)side * BGR + g) * 8 + ch) * 64 + t] =
        red[t] + red[64 + t] + red[128 + t] + red[192 + t];
}

// ---------------- tensor network + tail MLP ----------------
__global__ __launch_bounds__(256) void final_k(const float* __restrict__ poolp,
                                               const float* __restrict__ Wt, const float* __restrict__ Wtb,
                                               const float* __restrict__ tb, const int* __restrict__ hist_p,
                                               const float* __restrict__ W1, const float* __restrict__ b1,
                                               const float* __restrict__ Ws, const float* __restrict__ bs,
                                               float* __restrict__ out) {
    int b = blockIdx.x, t = threadIdx.x;
    __shared__ float cat[128];
    __shared__ float sacc[256];
    __shared__ float feat[32];
    __shared__ float hb[32];
    if (t < 128) {
        int side = t >> 6, f = t & 63;
        float s = 0.f;
#pragma unroll
        for (int ch = 0; ch < 8; ch++) s += poolp[(((size_t)side * BGR + b) * 8 + ch) * 64 + f];
        cat[t] = s;
    }
    __syncthreads();
    int k = t & 15, c = t >> 4;
    float acc = 0.f;
    for (int q = 0; q < 256; q++) {
        int ij = c * 256 + q;
        int i = ij >> 6, j = ij & 63;
        acc += cat[i] * cat[64 + j] * Wt[ij * KT + k];
    }
    sacc[t] = acc;
    __syncthreads();
    if (t < KT) {
        float sc = 0.f;
        for (int c2 = 0; c2 < 16; c2++) sc += sacc[c2 * 16 + t];
        float bt = 0.f;
        for (int i = 0; i < 128; i++) bt += cat[i] * Wtb[t * 128 + i];
        float tv = sc + bt + tb[t];
        feat[t] = tv > 0.f ? tv : 0.f;
        int hsum = 0;
#pragma unroll
        for (int j = 0; j < 16; j++) hsum += hist_p[((size_t)b * 16 + j) * BINS + t];
        feat[KT + t] = (float)hsum * (1.0f / (float)(NPG * NPG));
    }
    __syncthreads();
    if (t < BN) {
        float a = 0.f;
        for (int i = 0; i < KT + BINS; i++) a += feat[i] * W1[i * BN + t];
        a += b1[t];
        hb[t] = a > 0.f ? a : 0.f;
    }
    __syncthreads();
    if (t == 0) {
        float s = bs[0];
        for (int j = 0; j < BN; j++) s += hb[j] * Ws[j];
        out[b] = sigm(s);
    }
}

// ---------------- launch ----------------
extern "C" void kernel_launch(void* const* d_in, const int* in_sizes, int n_in,
                              void* d_out, int out_size, void* d_ws, size_t ws_size,
                              hipStream_t stream) {
    const float* x1   = (const float*)d_in[0];
    const float* x2   = (const float*)d_in[1];
    const int*   ei1  = (const int*)d_in[2];
    const int*   ei2  = (const int*)d_in[3];
    const float* Wc1  = (const float*)d_in[6];
    const float* bc1  = (const float*)d_in[7];
    const float* Wc2  = (const float*)d_in[8];
    const float* bc2  = (const float*)d_in[9];
    const float* Wc3  = (const float*)d_in[10];
    const float* bc3  = (const float*)d_in[11];
    const float* Watt = (const float*)d_in[12];
    const float* Wt   = (const float*)d_in[13];
    const float* Wtb  = (const float*)d_in[14];
    const float* tb   = (const float*)d_in[15];
    const float* W1   = (const float*)d_in[16];
    const float* b1   = (const float*)d_in[17];
    const float* Ws   = (const float*)d_in[18];
    const float* bs   = (const float*)d_in[19];
    float* out = (float*)d_out;

    // ---- workspace layout (~80 MB) ----
    char* wsb = (char*)d_ws;
    size_t o = 0;
    auto alloc = [&](size_t bytes) -> void* {
        void* p = wsb + o;
        o = (o + bytes + 255) & ~(size_t)255;
        return p;
    };
    bf* f1b  = (bf*)alloc((size_t)NTOT * F3 * 2);     //  8 MB
    bf* f2b  = (bf*)alloc((size_t)NTOT * F3 * 2);     //  8 MB
    bf* X    = (bf*)alloc((size_t)2 * NTOT * F2 * 2); // 24 MB (h2, both sides)
    bf* Y    = (bf*)alloc((size_t)2 * NTOT * F2 * 2); // 24 MB (t2/t3, both sides)
    int* off   = (int*)alloc((size_t)2 * (NTOT + 1) * 4);
    unsigned* ecsr = (unsigned*)alloc((size_t)2 * NEDGE * 4);        // 4 MB packed src|norm
    unsigned* bucket = (unsigned*)alloc((size_t)2 * 128 * GCAP * 4); // 6.3 MB
    int* gcount = (int*)alloc(256 * 4);
    float* dinv = (float*)alloc((size_t)2 * NTOT * 4);
    float* statmin = (float*)alloc((size_t)BGR * 16 * 4);
    float* statmax = (float*)alloc((size_t)BGR * 16 * 4);
    int* hist_p = (int*)alloc((size_t)BGR * 16 * BINS * 4);
    float* meanp = (float*)alloc((size_t)2 * BGR * 8 * 64 * 4);
    float* ctx   = (float*)alloc((size_t)2 * BGR * F3 * 4);
    float* poolp = (float*)alloc((size_t)2 * BGR * 8 * 64 * 4);
    bf* wt1 = (bf*)alloc((size_t)NL * F1 * 2);   // Wt1[F1][NL]
    bf* wt2 = (bf*)alloc((size_t)F1 * F2 * 2);   // Wt2[F2][F1]
    bf* wt3 = (bf*)alloc((size_t)F2 * F3 * 2);   // Wt3[F3][F2]
    (void)ws_size; (void)in_sizes; (void)n_in; (void)out_size;

    // init: zero gcount + weight transpose (single dispatch)
    init_k<<<(NL * F1 + F1 * F2 + F2 * F3 + 255) / 256, 256, 0, stream>>>(Wc1, Wc2, Wc3, wt1, wt2, wt3, gcount);

    // ---- CSR build: bucket by graph, then per-graph sort ----
    bucket_k<<<dim3(NEDGE / 1024, 2), 256, 0, stream>>>(ei1, ei2, gcount, bucket);
    csr_k<<<dim3(BGR, 2), 256, 0, stream>>>(bucket, gcount, off, dinv, ecsr);

    // ---- GCN stack (XCD-swizzled gather kernels) ----
    aggemm12_k<<<dim3(NTOT / 128, 2), 256, 0, stream>>>(x1, x2, off, ecsr, dinv, wt1, bc1, wt2, Y);
    agg_k<F2, 1><<<dim3((NTOT * (F2 / 4)) / 256, 2), 256, 0, stream>>>(Y, bc2, off, ecsr, dinv, X);
    gemmm_k<F2, F3, 0, 0><<<dim3(NTOT / 128, 2), 256, 0, stream>>>(X, wt3, nullptr, Y);
    aggf_k<F3><<<dim3((NTOT * (F3 / 4)) / 256, 2), 256, 0, stream>>>(Y, bc3, off, ecsr, dinv, f1b, f2b);

    // ---- sim minmax + mean partials (one dispatch) ----
    simmean_k<<<4096, 256, 0, stream>>>(f1b, f2b, statmin, statmax, meanp);
    // ---- sim hist + ctx (one dispatch) ----
    simhctx_k<<<2048 + 256, 256, 0, stream>>>(f1b, f2b, statmin, statmax, hist_p, meanp, Watt, ctx);
    // ---- coef + weighted pool partials ----
    cpool_k<<<dim3(BGR, 8, 2), 256, 0, stream>>>(f1b, f2b, ctx, poolp);

    // ---- tensor network + MLP tail ----
    final_k<<<BGR, 256, 0, stream>>>(poolp, Wt, Wtb, tb, hist_p, W1, b1, Ws, bs, out);
}